// Round 2
// baseline (2574.045 us; speedup 1.0000x reference)
//
#include <hip/hip_runtime.h>
#include <hip/hip_fp16.h>
#include <stdint.h>

#define B_   16
#define T_   30
#define NF   480       // frames = B*T
#define NN   2048      // nodes
#define EE   32768     // edges
#define FIN  8
#define HID  64
#define TEMP 128
#define BLK  1024
#define EPS  1e-5f

typedef unsigned int u32;
typedef unsigned short u16;

// ---------- helpers ----------
__device__ __forceinline__ u16 f2bf(float f) {           // RNE f32->bf16
  u32 u = __float_as_uint(f);
  u32 r = u + 0x7FFFu + ((u >> 16) & 1u);
  return (u16)(r >> 16);
}
__device__ __forceinline__ u32 pack2bf(float a, float b) {
  return (u32)f2bf(a) | ((u32)f2bf(b) << 16);
}
__device__ __forceinline__ float bflo(u32 w) { return __uint_as_float(w << 16); }
__device__ __forceinline__ float bfhi(u32 w) { return __uint_as_float(w & 0xFFFF0000u); }

// ---------- kernel A LDS layout (bytes) ----------
#define OFF_KEYS 0        // u32[2048]; also scan-aux u32[1024]; also hist/cur u32[128]
#define OFF_PERM 8192     // u16[2048]
#define OFF_DINV 12288    // f32[2048]
#define OFF_CNT  20480    // u32[2048] (cursor after scan)
#define OFF_SEG  28672    // u32[2049]
#define OFF_LENO 36872    // u16[2048]
#define OFF_XS   40968    // f32[2048*9]  (pad 9 vs bank conflicts)
#define OFF_W1   114704   // f32[512] (16B aligned)
#define OFF_S1   116752   // f32[64]
#define OFF_T1   117008   // f32[64]
// phase-2 staging reuses [0,147456) as bf16[2048][36]; dmap survives above it
#define OFF_DMAP 147456   // u16[2048]
#define LDS_A    151552

__device__ __forceinline__ void bitonic2048(u32* a, int t) {
  // 1024 threads -> exactly one pair per thread per pass
  for (int k = 2; k <= NN; k <<= 1) {
    for (int j = k >> 1; j > 0; j >>= 1) {
      int i = ((t & ~(j - 1)) << 1) | (t & (j - 1));
      int l = i | j;
      u32 x = a[i], y = a[l];
      bool up = ((i & k) == 0);
      if ((x > y) == up) { a[i] = y; a[l] = x; }
      __syncthreads();
    }
  }
}

__global__ __launch_bounds__(BLK, 4) void kA(
    const float* __restrict__ x, const int* __restrict__ ei, const float* __restrict__ ew,
    const int* __restrict__ nid, const float* __restrict__ W1, const float* __restrict__ b1,
    const float* __restrict__ g1, const float* __restrict__ be1,
    const float* __restrict__ m1, const float* __restrict__ v1,
    u32* __restrict__ rec_g, u16* __restrict__ h1_g)
{
  extern __shared__ unsigned char smem[];
  const int g = blockIdx.x;
  const int t = threadIdx.x;
  const int*   eig  = ei  + (size_t)g * 2 * EE;
  const float* ewg  = ew  + (size_t)g * EE;
  const int*   nidg = nid + (size_t)g * NN;
  const float* xg   = x   + (size_t)g * NN * FIN;
  u32* recf = rec_g + (size_t)g * EE;
  u16* h1f  = h1_g  + (size_t)g * (2 * NN * 32);   // two 32-feat planes, bf16, SLOT-major

  u32*  keys = (u32*)(smem + OFF_KEYS);
  u16*  perm = (u16*)(smem + OFF_PERM);
  float* dinv = (float*)(smem + OFF_DINV);
  u32*  cnt  = (u32*)(smem + OFF_CNT);
  u32*  seg  = (u32*)(smem + OFF_SEG);
  u16*  leno = (u16*)(smem + OFF_LENO);
  float* xs  = (float*)(smem + OFF_XS);
  float* W1s = (float*)(smem + OFF_W1);
  float* s1  = (float*)(smem + OFF_S1);
  float* t1  = (float*)(smem + OFF_T1);
  u16*  dmap = (u16*)(smem + OFF_DMAP);

  // ---- stable argsort of node_ids: key = (nid<<11)|idx (nid < 2^20) ----
  for (int i = t; i < NN; i += BLK) keys[i] = ((u32)nidg[i] << 11) | (u32)i;
  __syncthreads();
  bitonic2048(keys, t);
  for (int i = t; i < NN; i += BLK) perm[i] = (u16)(keys[i] & 2047u);

  // ---- degree (self-loop weight 1) + per-dst edge histogram ----
  for (int i = t; i < NN; i += BLK) { dinv[i] = 1.0f; cnt[i] = 0u; }
  __syncthreads();
  for (int e = t; e < EE; e += BLK) {
    int d = eig[EE + e];
    atomicAdd(&dinv[d], ewg[e]);
    atomicAdd(&cnt[d], 1u);
  }
  __syncthreads();
  for (int i = t; i < NN; i += BLK) dinv[i] = rsqrtf(dinv[i]);
  __syncthreads();

  // ---- exclusive scan cnt -> seg (2 elems/thread, 1024-wide scan) ----
  u32 c0 = cnt[2*t], c1 = cnt[2*t+1];
  u32* aux = keys;              // keys dead
  aux[t] = c0 + c1;
  __syncthreads();
  for (int off = 1; off < BLK; off <<= 1) {
    u32 v = (t >= off) ? aux[t - off] : 0u;
    __syncthreads();
    aux[t] += v;
    __syncthreads();
  }
  u32 base = (t == 0) ? 0u : aux[t - 1];
  seg[2*t] = base; seg[2*t+1] = base + c0;
  if (t == 0) seg[NN] = aux[BLK - 1];
  __syncthreads();

  // ---- length-bucketed dst order (balance wave divergence): O(N) histogram ----
  u32* hist = keys;             // aux dead
  u32* cur  = keys + 64;
  if (t < 128) hist[t] = 0u;
  __syncthreads();
  for (int i = t; i < NN; i += BLK) {
    u32 len = seg[i + 1] - seg[i];
    atomicAdd(&hist[len < 63u ? len : 63u], 1u);
  }
  __syncthreads();
  if (t < 64) {
    u32 v = hist[t], p = v;
    #pragma unroll
    for (int off = 1; off < 64; off <<= 1) {
      u32 o = __shfl_up(p, off, 64);
      if (t >= off) p += o;
    }
    cur[t] = p - v;             // exclusive prefix
  }
  __syncthreads();
  for (int i = t; i < NN; i += BLK) {
    u32 len = seg[i + 1] - seg[i];
    u32 slot = atomicAdd(&cur[len < 63u ? len : 63u], 1u);
    leno[slot] = (u16)i;
  }
  __syncthreads();

  // ---- counting-sort edges by dst into records (src<<16 | f16(norm)) ----
  for (int i = t; i < NN; i += BLK) cnt[i] = seg[i];   // cursor
  __syncthreads();
  for (int e = t; e < EE; e += BLK) {
    int s = eig[e], d = eig[EE + e];
    float nrm = dinv[s] * ewg[e] * dinv[d];
    u32 pos = atomicAdd(&cnt[d], 1u);
    __half hh = __float2half(nrm);
    recf[pos] = ((u32)s << 16) | (u32)__half_as_ushort(hh);
  }

  // ---- stage permuted x + layer-1 constants ----
  for (int i = t; i < NN; i += BLK) {
    int p = perm[i];
    const float4* xr = (const float4*)(xg + (size_t)p * FIN);
    float4 a = xr[0], b = xr[1];
    float* o = xs + i * 9;
    o[0]=a.x; o[1]=a.y; o[2]=a.z; o[3]=a.w; o[4]=b.x; o[5]=b.y; o[6]=b.z; o[7]=b.w;
  }
  for (int i = t; i < 512; i += BLK) W1s[i] = W1[i];
  if (t < 64) {
    float sc = g1[t] * rsqrtf(v1[t] + EPS);
    s1[t] = sc;
    t1[t] = (b1[t] - m1[t]) * sc + be1[t];   // fold bias+BN
  }
  __syncthreads();

  // per-thread slot info (cached: LDS metadata gets overwritten in phase 2)
  int dA[2]; u32 sA[2], eA[2]; float dvA[2];
  #pragma unroll
  for (int it = 0; it < 2; ++it) {
    int slot = it * BLK + t;
    int d = leno[slot];
    dA[it] = d; sA[it] = seg[d]; eA[it] = seg[d + 1]; dvA[it] = dinv[d];
    dmap[slot] = (u16)d;
  }
  __syncthreads();

  // ---- layer 1: aggregate x (8-dim), then @W1, BN, ReLU -> h1 slot-major ----
  for (int it = 0; it < 2; ++it) {
    int slot = it * BLK + t;
    float acc[8] = {0,0,0,0,0,0,0,0};
    u32 r = sA[it], e = eA[it];
#define P1(RC) { u32 rc_ = (RC); const float* xr_ = xs + (rc_ >> 16) * 9; \
    float nm_ = __half2float(__ushort_as_half((u16)(rc_ & 0xFFFFu))); \
    acc[0]+=nm_*xr_[0]; acc[1]+=nm_*xr_[1]; acc[2]+=nm_*xr_[2]; acc[3]+=nm_*xr_[3]; \
    acc[4]+=nm_*xr_[4]; acc[5]+=nm_*xr_[5]; acc[6]+=nm_*xr_[6]; acc[7]+=nm_*xr_[7]; }
    for (; r + 4 <= e; r += 4) {
      u32 q0 = recf[r], q1 = recf[r+1], q2 = recf[r+2], q3 = recf[r+3];
      P1(q0) P1(q1) P1(q2) P1(q3)
    }
    for (; r < e; ++r) { P1(recf[r]) }
#undef P1
    float dv2 = dvA[it] * dvA[it];
    const float* xd = xs + dA[it] * 9;
    #pragma unroll
    for (int k = 0; k < 8; ++k) acc[k] += dv2 * xd[k];
    float z[64];
    #pragma unroll
    for (int j = 0; j < 64; ++j) z[j] = 0.f;
    #pragma unroll
    for (int k = 0; k < 8; ++k) {
      float f = acc[k];
      const float4* wr = (const float4*)(W1s + k * 64);
      #pragma unroll
      for (int q = 0; q < 16; ++q) {
        float4 w = wr[q];
        z[4*q]   += f * w.x; z[4*q+1] += f * w.y;
        z[4*q+2] += f * w.z; z[4*q+3] += f * w.w;
      }
    }
    u32 pk[32];
    #pragma unroll
    for (int q = 0; q < 32; ++q) {
      float h0 = fmaxf(z[2*q]   * s1[2*q]   + t1[2*q],   0.f);
      float h1v = fmaxf(z[2*q+1] * s1[2*q+1] + t1[2*q+1], 0.f);
      pk[q] = pack2bf(h0, h1v);
    }
    uint4* o0 = (uint4*)(h1f + (size_t)slot * 32);                       // coalesced
    uint4* o1 = (uint4*)(h1f + (size_t)(NN * 32) + (size_t)slot * 32);
    o0[0] = make_uint4(pk[0],pk[1],pk[2],pk[3]);
    o0[1] = make_uint4(pk[4],pk[5],pk[6],pk[7]);
    o0[2] = make_uint4(pk[8],pk[9],pk[10],pk[11]);
    o0[3] = make_uint4(pk[12],pk[13],pk[14],pk[15]);
    o1[0] = make_uint4(pk[16],pk[17],pk[18],pk[19]);
    o1[1] = make_uint4(pk[20],pk[21],pk[22],pk[23]);
    o1[2] = make_uint4(pk[24],pk[25],pk[26],pk[27]);
    o1[3] = make_uint4(pk[28],pk[29],pk[30],pk[31]);
  }

  // ---- layer 2 aggregation of h1 (defer @W2 to kernel B); two feature halves ----
  // agg2 output aliases h1 planes (safe: full plane staged to LDS + barrier first)
  for (int half = 0; half < 2; ++half) {
    __syncthreads();   // previous phase's LDS readers + plane writers done
    const uint4* gp = (const uint4*)(h1f + (size_t)half * NN * 32);
    for (int i = t; i < NN * 4; i += BLK) {
      uint4 v = gp[i];                       // coalesced slot-major read
      int slot_ = i >> 2, q = i & 3;
      int row = dmap[slot_];                 // scatter on the cheap (LDS) side
      uint2* lp = (uint2*)(smem + row * 72 + q * 16);   // row stride 36 bf16 = 72B
      lp[0] = make_uint2(v.x, v.y);
      lp[1] = make_uint2(v.z, v.w);
    }
    __syncthreads();
    for (int it = 0; it < 2; ++it) {
      int slot = it * BLK + t;
      float acc[32];
      #pragma unroll
      for (int k = 0; k < 32; ++k) acc[k] = 0.f;
      u32 r = sA[it], e = eA[it];
#define P2(RC) { u32 rc_ = (RC); const uint2* rp_ = (const uint2*)(smem + (rc_ >> 16) * 72); \
      float nm_ = __half2float(__ushort_as_half((u16)(rc_ & 0xFFFFu))); \
      uint2 w0_=rp_[0], w1_=rp_[1], w2_=rp_[2], w3_=rp_[3]; \
      uint2 w4_=rp_[4], w5_=rp_[5], w6_=rp_[6], w7_=rp_[7]; \
      acc[0]+=nm_*bflo(w0_.x);  acc[1]+=nm_*bfhi(w0_.x);  acc[2]+=nm_*bflo(w0_.y);  acc[3]+=nm_*bfhi(w0_.y); \
      acc[4]+=nm_*bflo(w1_.x);  acc[5]+=nm_*bfhi(w1_.x);  acc[6]+=nm_*bflo(w1_.y);  acc[7]+=nm_*bfhi(w1_.y); \
      acc[8]+=nm_*bflo(w2_.x);  acc[9]+=nm_*bfhi(w2_.x);  acc[10]+=nm_*bflo(w2_.y); acc[11]+=nm_*bfhi(w2_.y); \
      acc[12]+=nm_*bflo(w3_.x); acc[13]+=nm_*bfhi(w3_.x); acc[14]+=nm_*bflo(w3_.y); acc[15]+=nm_*bfhi(w3_.y); \
      acc[16]+=nm_*bflo(w4_.x); acc[17]+=nm_*bfhi(w4_.x); acc[18]+=nm_*bflo(w4_.y); acc[19]+=nm_*bfhi(w4_.y); \
      acc[20]+=nm_*bflo(w5_.x); acc[21]+=nm_*bfhi(w5_.x); acc[22]+=nm_*bflo(w5_.y); acc[23]+=nm_*bfhi(w5_.y); \
      acc[24]+=nm_*bflo(w6_.x); acc[25]+=nm_*bfhi(w6_.x); acc[26]+=nm_*bflo(w6_.y); acc[27]+=nm_*bfhi(w6_.y); \
      acc[28]+=nm_*bflo(w7_.x); acc[29]+=nm_*bfhi(w7_.x); acc[30]+=nm_*bflo(w7_.y); acc[31]+=nm_*bfhi(w7_.y); }
      for (; r + 4 <= e; r += 4) {
        u32 q0 = recf[r], q1 = recf[r+1], q2 = recf[r+2], q3 = recf[r+3];
        P2(q0) P2(q1) P2(q2) P2(q3)
      }
      for (; r < e; ++r) { P2(recf[r]) }
#undef P2
      float dv2 = dvA[it] * dvA[it];
      const uint2* rd = (const uint2*)(smem + dA[it] * 72);
      #pragma unroll
      for (int q = 0; q < 8; ++q) {
        uint2 w = rd[q];
        acc[4*q]   += dv2 * bflo(w.x);
        acc[4*q+1] += dv2 * bfhi(w.x);
        acc[4*q+2] += dv2 * bflo(w.y);
        acc[4*q+3] += dv2 * bfhi(w.y);
      }
      u32 pk[16];
      #pragma unroll
      for (int q = 0; q < 16; ++q) pk[q] = pack2bf(acc[2*q], acc[2*q+1]);
      uint4* op = (uint4*)(h1f + (size_t)half * NN * 32 + (size_t)slot * 32);  // coalesced
      op[0] = make_uint4(pk[0],pk[1],pk[2],pk[3]);
      op[1] = make_uint4(pk[4],pk[5],pk[6],pk[7]);
      op[2] = make_uint4(pk[8],pk[9],pk[10],pk[11]);
      op[3] = make_uint4(pk[12],pk[13],pk[14],pk[15]);
    }
  }
}

// ---- kernel B: h2 = ReLU(BN(agg2 @ W2 + b2)); frame mean (row order irrelevant) ----
__global__ __launch_bounds__(512, 2) void kB(
    const u16* __restrict__ agg, const float* __restrict__ W2, const float* __restrict__ b2,
    const float* __restrict__ g2, const float* __restrict__ be2,
    const float* __restrict__ m2, const float* __restrict__ v2,
    float* __restrict__ frames)
{
  const int g = blockIdx.x;
  const int tid = threadIdx.x;
  const int lane = tid & 63;
  const int wid = tid >> 6;       // 8 waves
  float w2c[64];
  #pragma unroll
  for (int k = 0; k < 64; ++k) w2c[k] = W2[k * 64 + lane];
  float sc = g2[lane] * rsqrtf(v2[lane] + EPS);
  float tc = (b2[lane] - m2[lane]) * sc + be2[lane];
  const uint4* p0 = (const uint4*)(agg + (size_t)g * NN * 64);
  const uint4* p1 = p0 + NN * 4;
  float macc = 0.f;
  for (int i = 0; i < 256; ++i) {
    int m = wid * 256 + i;
    uint4 a0 = p0[m*4+0], a1 = p0[m*4+1], a2 = p0[m*4+2], a3 = p0[m*4+3];
    uint4 b0 = p1[m*4+0], b1_ = p1[m*4+1], b2_ = p1[m*4+2], b3_ = p1[m*4+3];
    float z = 0.f;
#define ACC4(u, base) \
    z += bflo(u.x)*w2c[base+0] + bfhi(u.x)*w2c[base+1] + bflo(u.y)*w2c[base+2] + bfhi(u.y)*w2c[base+3] \
       + bflo(u.z)*w2c[base+4] + bfhi(u.z)*w2c[base+5] + bflo(u.w)*w2c[base+6] + bfhi(u.w)*w2c[base+7];
    ACC4(a0, 0)  ACC4(a1, 8)  ACC4(a2, 16)  ACC4(a3, 24)
    ACC4(b0, 32) ACC4(b1_, 40) ACC4(b2_, 48) ACC4(b3_, 56)
#undef ACC4
    float h = fmaxf(z * sc + tc, 0.f);
    macc += h;
  }
  __shared__ float part[8][64];
  part[wid][lane] = macc;
  __syncthreads();
  if (tid < 64) {
    float s = 0.f;
    #pragma unroll
    for (int w = 0; w < 8; ++w) s += part[w][tid];
    frames[g * 64 + tid] = s * (1.0f / 2048.0f);
  }
}

// ---- kernel C: GRU over T=30 + classifier; one block per batch element ----
__global__ __launch_bounds__(384, 2) void kC(
    const float* __restrict__ frames,
    const float* __restrict__ Wih, const float* __restrict__ Whh,
    const float* __restrict__ bih, const float* __restrict__ bhh,
    const float* __restrict__ Wc1, const float* __restrict__ bc1,
    const float* __restrict__ Wc2, const float* __restrict__ bc2,
    float* __restrict__ out)
{
  const int b = blockIdx.x;
  const int j = threadIdx.x;     // 384 = 3*TEMP gate rows
  __shared__ float xt[64], h[128], GI[384], GH[384], hid[64];
  float wih[64], whh[128];
  const float4* wi4 = (const float4*)(Wih + (size_t)j * 64);
  #pragma unroll
  for (int q = 0; q < 16; ++q) { float4 v = wi4[q]; wih[4*q]=v.x; wih[4*q+1]=v.y; wih[4*q+2]=v.z; wih[4*q+3]=v.w; }
  const float4* wh4 = (const float4*)(Whh + (size_t)j * 128);
  #pragma unroll
  for (int q = 0; q < 32; ++q) { float4 v = wh4[q]; whh[4*q]=v.x; whh[4*q+1]=v.y; whh[4*q+2]=v.z; whh[4*q+3]=v.w; }
  float bi = bih[j], bh = bhh[j];
  if (j < 128) h[j] = 0.f;
  __syncthreads();
  for (int t = 0; t < T_; ++t) {
    if (j < 64) xt[j] = frames[((size_t)b * T_ + t) * 64 + j];
    __syncthreads();
    float gi = bi, gh = bh;
    #pragma unroll
    for (int k = 0; k < 64; ++k) gi += xt[k] * wih[k];
    #pragma unroll
    for (int k = 0; k < 128; ++k) gh += h[k] * whh[k];
    GI[j] = gi; GH[j] = gh;
    __syncthreads();
    if (j < 128) {
      float r = 1.f / (1.f + __expf(-(GI[j] + GH[j])));
      float z = 1.f / (1.f + __expf(-(GI[128 + j] + GH[128 + j])));
      float n = tanhf(GI[256 + j] + r * GH[256 + j]);
      h[j] = (1.f - z) * n + z * h[j];
    }
    __syncthreads();
  }
  if (j < 64) {
    float a = bc1[j];
    #pragma unroll 4
    for (int k = 0; k < 128; ++k) a += h[k] * Wc1[k * 64 + j];
    hid[j] = fmaxf(a, 0.f);
  }
  __syncthreads();
  if (j < 2) {
    float o = bc2[j];
    #pragma unroll
    for (int k = 0; k < 64; ++k) o += hid[k] * Wc2[k * 2 + j];
    out[b * 2 + j] = o;
  }
}

// ---------- launch ----------
extern "C" void kernel_launch(void* const* d_in, const int* in_sizes, int n_in,
                              void* d_out, int out_size, void* d_ws, size_t ws_size,
                              hipStream_t stream) {
  const float* x   = (const float*)d_in[0];
  const int*   ei  = (const int*)d_in[1];
  const float* ew  = (const float*)d_in[2];
  const int*   nid = (const int*)d_in[3];
  const float* W1  = (const float*)d_in[4];
  const float* b1  = (const float*)d_in[5];
  const float* W2  = (const float*)d_in[6];
  const float* b2  = (const float*)d_in[7];
  const float* g1  = (const float*)d_in[8];
  const float* be1 = (const float*)d_in[9];
  const float* m1  = (const float*)d_in[10];
  const float* v1  = (const float*)d_in[11];
  const float* g2  = (const float*)d_in[12];
  const float* be2 = (const float*)d_in[13];
  const float* m2  = (const float*)d_in[14];
  const float* v2  = (const float*)d_in[15];
  const float* Wih = (const float*)d_in[16];
  const float* Whh = (const float*)d_in[17];
  const float* bih = (const float*)d_in[18];
  const float* bhh = (const float*)d_in[19];
  const float* Wc1 = (const float*)d_in[20];
  const float* bc1 = (const float*)d_in[21];
  const float* Wc2 = (const float*)d_in[22];
  const float* bc2 = (const float*)d_in[23];
  float* out = (float*)d_out;

  // workspace layout (bytes): records | h1/agg2 bf16 planes | frames
  const size_t REC_OFF = 0;                                  // 480*32768*4  = 62,914,560
  const size_t H1_OFF  = 62914560;                           // 480*2048*64*2 = 125,829,120
  const size_t FR_OFF  = 188743680;                          // 480*64*4 = 122,880
  if (ws_size < (size_t)188866560) return;                   // insufficient scratch

  u32* rec   = (u32*)((char*)d_ws + REC_OFF);
  u16* h1    = (u16*)((char*)d_ws + H1_OFF);
  float* frm = (float*)((char*)d_ws + FR_OFF);

  hipFuncSetAttribute((const void*)kA, hipFuncAttributeMaxDynamicSharedMemorySize, LDS_A);

  kA<<<NF, BLK, LDS_A, stream>>>(x, ei, ew, nid, W1, b1, g1, be1, m1, v1, rec, h1);
  kB<<<NF, 512, 0, stream>>>(h1, W2, b2, g2, be2, m2, v2, frm);
  kC<<<B_, 384, 0, stream>>>(frm, Wih, Whh, bih, bhh, Wc1, bc1, Wc2, bc2, out);
}

// Round 3
// 1173.594 us; speedup vs baseline: 2.1933x; 2.1933x over previous
//
#include <hip/hip_runtime.h>
#include <hip/hip_fp16.h>
#include <stdint.h>

#define B_   16
#define T_   30
#define NF   480       // frames = B*T
#define NN   2048      // nodes
#define EE   32768     // edges
#define EPS  1e-5f

typedef unsigned int u32;
typedef unsigned short u16;

// ---------- helpers ----------
__device__ __forceinline__ u16 f2bf(float f) {           // RNE f32->bf16
  u32 u = __float_as_uint(f);
  u32 r = u + 0x7FFFu + ((u >> 16) & 1u);
  return (u16)(r >> 16);
}
__device__ __forceinline__ u32 pack2bf(float a, float b) {
  return (u32)f2bf(a) | ((u32)f2bf(b) << 16);
}
__device__ __forceinline__ float bflo(u32 w) { return __uint_as_float(w << 16); }
__device__ __forceinline__ float bfhi(u32 w) { return __uint_as_float(w & 0xFFFF0000u); }
__device__ __forceinline__ u16 f2h(float f) { return __half_as_ushort(__float2half(f)); }
__device__ __forceinline__ float h2f(u16 h) { return __half2float(__ushort_as_half(h)); }

// =========================================================================
// kPre: sort node_ids, degree, CSR segments, length-bucket, counting-sort
//       records into LDS, coalesced stream-out.  1024 thr, 144KB LDS.
// =========================================================================
#define KP_KEYS 0          // u32[2048]  (also scan aux u32[1024])
#define KP_SEG  8192       // u32[2049]
#define KP_LENO 16400      // u16[2048]
#define KP_HIST 20496      // u32[64]
#define KP_CUR  20752      // u32[64]
#define KP_DINV 131072     // f32[2048]
#define KP_CNT  139264     // u32[2048]
#define KP_REC  0          // u32[32768] phase 2 (keys/seg/leno/hist dead)
#define KP_LDS  147456

__global__ __launch_bounds__(1024) void kPre(
    const int* __restrict__ ei, const float* __restrict__ ew, const int* __restrict__ nid,
    u32* __restrict__ recG, u32* __restrict__ segG, u32* __restrict__ permG,
    u32* __restrict__ lenoG, u32* __restrict__ dvG)
{
  extern __shared__ unsigned char smem[];
  const int g = blockIdx.x, t = threadIdx.x;
  const int*   eig  = ei  + (size_t)g * 2 * EE;
  const float* ewg  = ew  + (size_t)g * EE;
  const int*   nidg = nid + (size_t)g * NN;

  u32*  keys = (u32*)(smem + KP_KEYS);
  u32*  seg  = (u32*)(smem + KP_SEG);
  u16*  leno = (u16*)(smem + KP_LENO);
  u32*  hist = (u32*)(smem + KP_HIST);
  u32*  cur  = (u32*)(smem + KP_CUR);
  float* dinv = (float*)(smem + KP_DINV);
  u32*  cnt  = (u32*)(smem + KP_CNT);
  u32*  rec  = (u32*)(smem + KP_REC);

  // load keys (stable sort: key = nid<<11 | idx), init dinv/cnt
  keys[t]        = ((u32)nidg[t] << 11) | (u32)t;
  keys[t + 1024] = ((u32)nidg[t + 1024] << 11) | (u32)(t + 1024);
  dinv[t] = 1.0f; dinv[t + 1024] = 1.0f;
  cnt[t] = 0u; cnt[t + 1024] = 0u;
  __syncthreads();

  // bitonic sort, 1 pair/thread/pass
  for (int k = 2; k <= NN; k <<= 1) {
    for (int j = k >> 1; j > 0; j >>= 1) {
      int i = ((t & ~(j - 1)) << 1) | (t & (j - 1));
      int l = i | j;
      u32 x = keys[i], y = keys[l];
      bool up = ((i & k) == 0);
      if ((x > y) == up) { keys[i] = y; keys[l] = x; }
      __syncthreads();
    }
  }

  // export perm (u16 pairs packed in u32)
  permG[(size_t)g * 1024 + t] = (keys[2*t] & 2047u) | ((keys[2*t+1] & 2047u) << 16);

  // degree + per-dst histogram
  for (int e = t; e < EE; e += 1024) {
    int d = eig[EE + e];
    atomicAdd(&dinv[d], ewg[e]);
    atomicAdd(&cnt[d], 1u);
  }
  __syncthreads();   // also fences perm-export reads of keys before aux reuse

  float r0 = rsqrtf(dinv[2*t]), r1 = rsqrtf(dinv[2*t+1]);
  dinv[2*t] = r0; dinv[2*t+1] = r1;
  dvG[(size_t)g * 1024 + t] = (u32)f2h(r0 * r0) | ((u32)f2h(r1 * r1) << 16);

  // exclusive scan cnt -> seg
  u32 c0 = cnt[2*t], c1 = cnt[2*t+1];
  u32* aux = keys;                    // keys dead
  aux[t] = c0 + c1;
  __syncthreads();
  for (int off = 1; off < 1024; off <<= 1) {
    u32 v = (t >= off) ? aux[t - off] : 0u;
    __syncthreads();
    aux[t] += v;
    __syncthreads();
  }
  u32 base = (t == 0) ? 0u : aux[t - 1];
  seg[2*t] = base; seg[2*t+1] = base + c0;
  if (t == 0) seg[NN] = aux[1023];
  __syncthreads();

  // export packed segments (start | len<<16)
  {
    u32 s0 = seg[2*t],   l0 = seg[2*t+1] - s0;
    u32 s1_ = seg[2*t+1], l1 = seg[2*t+2] - s1_;
    segG[(size_t)g * 2048 + 2*t]     = (s0  & 0xFFFFu) | (l0 << 16);
    segG[(size_t)g * 2048 + 2*t + 1] = (s1_ & 0xFFFFu) | (l1 << 16);
  }

  // length-bucket slot order (O(N) histogram)
  if (t < 64) hist[t] = 0u;
  __syncthreads();
  for (int i = t; i < NN; i += 1024) {
    u32 len = seg[i+1] - seg[i];
    atomicAdd(&hist[len < 63u ? len : 63u], 1u);
  }
  __syncthreads();
  if (t < 64) {
    u32 v = hist[t], p = v;
    #pragma unroll
    for (int off = 1; off < 64; off <<= 1) {
      u32 o = __shfl_up(p, off, 64);
      if (t >= off) p += o;
    }
    cur[t] = p - v;
  }
  __syncthreads();
  for (int i = t; i < NN; i += 1024) {
    u32 len = seg[i+1] - seg[i];
    u32 slot = atomicAdd(&cur[len < 63u ? len : 63u], 1u);
    leno[slot] = (u16)i;
  }
  __syncthreads();
  lenoG[(size_t)g * 1024 + t] = (u32)leno[2*t] | ((u32)leno[2*t+1] << 16);

  // cursor for counting sort
  cnt[2*t] = seg[2*t]; cnt[2*t+1] = seg[2*t+1];
  __syncthreads();     // after this, keys/seg/leno/hist are dead -> rec overlays

  // counting-sort edges -> rec LDS (src<<16 | f16(norm))
  for (int e = t; e < EE; e += 1024) {
    int s = eig[e], d = eig[EE + e];
    float nrm = dinv[s] * ewg[e] * dinv[d];
    u32 pos = atomicAdd(&cnt[d], 1u);
    rec[pos] = ((u32)s << 16) | (u32)f2h(nrm);
  }
  __syncthreads();

  // coalesced stream-out
  uint4* rg = (uint4*)(recG + (size_t)g * EE);
  const uint4* rl = (const uint4*)rec;
  for (int i = t; i < EE / 4; i += 1024) rg[i] = rl[i];
}

// =========================================================================
// kL1: layer-1.  Aggregate x (8-dim) per dst via record walk (xs in LDS),
//      z[64] = acc @ W1, BN+ReLU, write h1 as 4 slot-major quarter-planes.
// =========================================================================
#define L1_XS  0        // f32[2048][8] = 65536 (32B rows, b128-aligned)
#define L1_W1  65536    // f32[512]
#define L1_S1  67584    // f32[64]
#define L1_T1  67840    // f32[64]
#define L1_LDS 68096

__global__ __launch_bounds__(512, 2) void kL1(
    const float* __restrict__ x, const u32* __restrict__ recG, const u32* __restrict__ segG,
    const u32* __restrict__ permG, const u32* __restrict__ lenoG, const u32* __restrict__ dvG,
    const float* __restrict__ W1, const float* __restrict__ b1,
    const float* __restrict__ g1, const float* __restrict__ be1,
    const float* __restrict__ m1, const float* __restrict__ v1,
    u16* __restrict__ h1G)
{
  extern __shared__ unsigned char smem[];
  const int g = blockIdx.x, t = threadIdx.x;
  const u32* recf = recG + (size_t)g * EE;
  float* W1s = (float*)(smem + L1_W1);
  float* s1  = (float*)(smem + L1_S1);
  float* t1  = (float*)(smem + L1_T1);

  // stage permuted x rows
  const u16* pG = (const u16*)(permG + (size_t)g * 1024);
  for (int i = t; i < NN; i += 512) {
    int p = pG[i];
    const float4* xr = (const float4*)(x + ((size_t)g * NN + p) * 8);
    float4 a = xr[0], b = xr[1];
    float4* o = (float4*)(smem + (size_t)i * 32);
    o[0] = a; o[1] = b;
  }
  if (t < 512) W1s[t] = W1[t];
  if (t < 64) {
    float sc = g1[t] * rsqrtf(v1[t] + EPS);
    s1[t] = sc;
    t1[t] = (b1[t] - m1[t]) * sc + be1[t];
  }

  // slot meta (zigzag slot assignment balances walk sums per thread)
  const u16* lG = (const u16*)(lenoG + (size_t)g * 1024);
  const u16* dG = (const u16*)(dvG + (size_t)g * 1024);
  int dA[4], slotA[4]; u32 sA[4], eA[4]; float dvA[4];
  #pragma unroll
  for (int it = 0; it < 4; ++it) {
    int slot = it * 512 + ((it & 1) ? (511 - t) : t);
    int d = lG[slot];
    u32 sp = segG[(size_t)g * 2048 + d];
    slotA[it] = slot; dA[it] = d;
    sA[it] = sp & 0xFFFFu; eA[it] = (sp & 0xFFFFu) + (sp >> 16);
    dvA[it] = h2f(dG[d]);                // = dinv[d]^2
  }
  __syncthreads();

#define P1(RC) { u32 rc_ = (RC); int s_ = (int)(rc_ >> 16); \
    float nm_ = h2f((u16)(rc_ & 0xFFFFu)); \
    const float4* xp_ = (const float4*)(smem + (size_t)s_ * 32); \
    float4 a_ = xp_[0], b_ = xp_[1]; \
    ac0 += nm_*a_.x; ac1 += nm_*a_.y; ac2 += nm_*a_.z; ac3 += nm_*a_.w; \
    ac4 += nm_*b_.x; ac5 += nm_*b_.y; ac6 += nm_*b_.z; ac7 += nm_*b_.w; }

  for (int it = 0; it < 4; ++it) {
    float ac0=0,ac1=0,ac2=0,ac3=0,ac4=0,ac5=0,ac6=0,ac7=0;
    u32 r = sA[it], e = eA[it];
    for (; r + 4 <= e; r += 4) {
      u32 q0 = recf[r], q1 = recf[r+1], q2 = recf[r+2], q3 = recf[r+3];
      P1(q0) P1(q1) P1(q2) P1(q3)
    }
    for (; r < e; ++r) { P1(recf[r]) }
    {  // self-loop (dvA = dinv^2)
      const float4* xd = (const float4*)(smem + (size_t)dA[it] * 32);
      float4 a = xd[0], b = xd[1];
      float dv = dvA[it];
      ac0 += dv*a.x; ac1 += dv*a.y; ac2 += dv*a.z; ac3 += dv*a.w;
      ac4 += dv*b.x; ac5 += dv*b.y; ac6 += dv*b.z; ac7 += dv*b.w;
    }
    float acc[8] = {ac0,ac1,ac2,ac3,ac4,ac5,ac6,ac7};
    float z[64];
    #pragma unroll
    for (int j = 0; j < 64; ++j) z[j] = 0.f;
    #pragma unroll
    for (int k = 0; k < 8; ++k) {
      float f = acc[k];
      const float4* wr = (const float4*)(W1s + k * 64);
      #pragma unroll
      for (int q = 0; q < 16; ++q) {
        float4 w = wr[q];
        z[4*q]   += f * w.x; z[4*q+1] += f * w.y;
        z[4*q+2] += f * w.z; z[4*q+3] += f * w.w;
      }
    }
    // BN + ReLU + bf16 pack, write 4 quarter-planes slot-major
    int slot = slotA[it];
    #pragma unroll
    for (int p = 0; p < 4; ++p) {
      u32 pk[8];
      #pragma unroll
      for (int j = 0; j < 8; ++j) {
        int f0 = p * 16 + 2 * j;
        float h0 = fmaxf(z[f0]   * s1[f0]   + t1[f0],   0.f);
        float h1v = fmaxf(z[f0+1] * s1[f0+1] + t1[f0+1], 0.f);
        pk[j] = pack2bf(h0, h1v);
      }
      uint4* op = (uint4*)h1G + ((size_t)(g * 4 + p) * NN + slot) * 2;
      op[0] = make_uint4(pk[0], pk[1], pk[2], pk[3]);
      op[1] = make_uint4(pk[4], pk[5], pk[6], pk[7]);
    }
  }
#undef P1
}

// =========================================================================
// kL2: layer-2 aggregation, 4 passes of 16 features; h1 quarter staged in
//      LDS (node-indexed, 32B rows), agg overwrites h1 planes in place.
// =========================================================================
#define L2_ST   0        // bf16[2048][16] = 65536
#define L2_LENO 65536    // u16[2048]
#define L2_LDS  69632

__global__ __launch_bounds__(512, 2) void kL2(
    const u32* __restrict__ recG, const u32* __restrict__ segG,
    const u32* __restrict__ lenoG, const u32* __restrict__ dvG,
    u16* __restrict__ h1G)
{
  extern __shared__ unsigned char smem[];
  const int g = blockIdx.x, t = threadIdx.x;
  const u32* recf = recG + (size_t)g * EE;
  u16* lenoL = (u16*)(smem + L2_LENO);

  // stage leno (4KB)
  if (t < 256) ((uint4*)lenoL)[t] = ((const uint4*)(lenoG + (size_t)g * 1024))[t];
  __syncthreads();

  const u16* dG = (const u16*)(dvG + (size_t)g * 1024);
  int dA[4], slotA[4]; u32 sA[4], eA[4]; float dvA[4];
  #pragma unroll
  for (int it = 0; it < 4; ++it) {
    int slot = it * 512 + ((it & 1) ? (511 - t) : t);
    int d = lenoL[slot];
    u32 sp = segG[(size_t)g * 2048 + d];
    slotA[it] = slot; dA[it] = d;
    sA[it] = sp & 0xFFFFu; eA[it] = (sp & 0xFFFFu) + (sp >> 16);
    dvA[it] = h2f(dG[d]);
  }

#define P2(RC) { u32 rc_ = (RC); int s_ = (int)(rc_ >> 16); \
    float nm_ = h2f((u16)(rc_ & 0xFFFFu)); \
    const uint4* rp_ = (const uint4*)(smem + (size_t)s_ * 32); \
    uint4 lo_ = rp_[0], hi_ = rp_[1]; \
    acc[0]+=nm_*bflo(lo_.x);  acc[1]+=nm_*bfhi(lo_.x);  acc[2]+=nm_*bflo(lo_.y);  acc[3]+=nm_*bfhi(lo_.y); \
    acc[4]+=nm_*bflo(lo_.z);  acc[5]+=nm_*bfhi(lo_.z);  acc[6]+=nm_*bflo(lo_.w);  acc[7]+=nm_*bfhi(lo_.w); \
    acc[8]+=nm_*bflo(hi_.x);  acc[9]+=nm_*bfhi(hi_.x);  acc[10]+=nm_*bflo(hi_.y); acc[11]+=nm_*bfhi(hi_.y); \
    acc[12]+=nm_*bflo(hi_.z); acc[13]+=nm_*bfhi(hi_.z); acc[14]+=nm_*bflo(hi_.w); acc[15]+=nm_*bfhi(hi_.w); }

  for (int p = 0; p < 4; ++p) {
    __syncthreads();
    // stage quarter-plane p, scattered to node rows via leno
    const uint4* plane = (const uint4*)h1G + (size_t)(g * 4 + p) * NN * 2;
    for (int i = t; i < NN * 2; i += 512) {
      uint4 v = plane[i];
      int sl = i >> 1, hf = i & 1;
      int d2 = lenoL[sl];
      *(uint4*)(smem + (size_t)d2 * 32 + hf * 16) = v;
    }
    __syncthreads();

    for (int it = 0; it < 4; ++it) {
      float acc[16];
      #pragma unroll
      for (int k = 0; k < 16; ++k) acc[k] = 0.f;
      u32 r = sA[it], e = eA[it];
      for (; r + 4 <= e; r += 4) {
        u32 q0 = recf[r], q1 = recf[r+1], q2 = recf[r+2], q3 = recf[r+3];
        P2(q0) P2(q1) P2(q2) P2(q3)
      }
      for (; r < e; ++r) { P2(recf[r]) }
      {  // self-loop
        const uint4* rd = (const uint4*)(smem + (size_t)dA[it] * 32);
        uint4 lo = rd[0], hi = rd[1];
        float dv = dvA[it];
        acc[0]+=dv*bflo(lo.x);  acc[1]+=dv*bfhi(lo.x);  acc[2]+=dv*bflo(lo.y);  acc[3]+=dv*bfhi(lo.y);
        acc[4]+=dv*bflo(lo.z);  acc[5]+=dv*bfhi(lo.z);  acc[6]+=dv*bflo(lo.w);  acc[7]+=dv*bfhi(lo.w);
        acc[8]+=dv*bflo(hi.x);  acc[9]+=dv*bfhi(hi.x);  acc[10]+=dv*bflo(hi.y); acc[11]+=dv*bfhi(hi.y);
        acc[12]+=dv*bflo(hi.z); acc[13]+=dv*bfhi(hi.z); acc[14]+=dv*bflo(hi.w); acc[15]+=dv*bfhi(hi.w);
      }
      u32 pk[8];
      #pragma unroll
      for (int j = 0; j < 8; ++j) pk[j] = pack2bf(acc[2*j], acc[2*j+1]);
      uint4* op = (uint4*)h1G + ((size_t)(g * 4 + p) * NN + slotA[it]) * 2;
      op[0] = make_uint4(pk[0], pk[1], pk[2], pk[3]);
      op[1] = make_uint4(pk[4], pk[5], pk[6], pk[7]);
    }
  }
#undef P2
}

// =========================================================================
// kB: h2 = ReLU(BN(agg @ W2 + b2)); frame mean over slots (order-free)
// =========================================================================
__global__ __launch_bounds__(512, 2) void kB(
    const u16* __restrict__ agg, const float* __restrict__ W2, const float* __restrict__ b2,
    const float* __restrict__ g2, const float* __restrict__ be2,
    const float* __restrict__ m2, const float* __restrict__ v2,
    float* __restrict__ frames)
{
  const int g = blockIdx.x, tid = threadIdx.x, lane = tid & 63, wid = tid >> 6;
  float w2c[64];
  #pragma unroll
  for (int k = 0; k < 64; ++k) w2c[k] = W2[k * 64 + lane];
  float sc = g2[lane] * rsqrtf(v2[lane] + EPS);
  float tc = (b2[lane] - m2[lane]) * sc + be2[lane];
  const uint4* pp = (const uint4*)agg;
  size_t b0 = (size_t)(g * 4 + 0) * NN * 2, b1_ = (size_t)(g * 4 + 1) * NN * 2;
  size_t b2_ = (size_t)(g * 4 + 2) * NN * 2, b3 = (size_t)(g * 4 + 3) * NN * 2;
  float macc = 0.f;
  for (int i = 0; i < 256; ++i) {
    int m = wid * 256 + i;
    uint4 q0 = pp[b0 + m*2], q1 = pp[b0 + m*2 + 1];
    uint4 q2 = pp[b1_ + m*2], q3 = pp[b1_ + m*2 + 1];
    uint4 q4 = pp[b2_ + m*2], q5 = pp[b2_ + m*2 + 1];
    uint4 q6 = pp[b3 + m*2], q7 = pp[b3 + m*2 + 1];
    float z = 0.f;
#define ACC4(u, base) \
    z += bflo(u.x)*w2c[base+0] + bfhi(u.x)*w2c[base+1] + bflo(u.y)*w2c[base+2] + bfhi(u.y)*w2c[base+3] \
       + bflo(u.z)*w2c[base+4] + bfhi(u.z)*w2c[base+5] + bflo(u.w)*w2c[base+6] + bfhi(u.w)*w2c[base+7];
    ACC4(q0, 0)  ACC4(q1, 8)  ACC4(q2, 16) ACC4(q3, 24)
    ACC4(q4, 32) ACC4(q5, 40) ACC4(q6, 48) ACC4(q7, 56)
#undef ACC4
    macc += fmaxf(z * sc + tc, 0.f);
  }
  __shared__ float part[8][64];
  part[wid][lane] = macc;
  __syncthreads();
  if (tid < 64) {
    float s = 0.f;
    #pragma unroll
    for (int w = 0; w < 8; ++w) s += part[w][tid];
    frames[g * 64 + tid] = s * (1.0f / 2048.0f);
  }
}

// =========================================================================
// kC: GRU over T=30 + classifier; one block per batch element
// =========================================================================
__global__ __launch_bounds__(384, 2) void kC(
    const float* __restrict__ frames,
    const float* __restrict__ Wih, const float* __restrict__ Whh,
    const float* __restrict__ bih, const float* __restrict__ bhh,
    const float* __restrict__ Wc1, const float* __restrict__ bc1,
    const float* __restrict__ Wc2, const float* __restrict__ bc2,
    float* __restrict__ out)
{
  const int b = blockIdx.x;
  const int j = threadIdx.x;     // 384 = 3*TEMP gate rows
  __shared__ float xt[64], h[128], GI[384], GH[384], hid[64];
  float wih[64], whh[128];
  const float4* wi4 = (const float4*)(Wih + (size_t)j * 64);
  #pragma unroll
  for (int q = 0; q < 16; ++q) { float4 v = wi4[q]; wih[4*q]=v.x; wih[4*q+1]=v.y; wih[4*q+2]=v.z; wih[4*q+3]=v.w; }
  const float4* wh4 = (const float4*)(Whh + (size_t)j * 128);
  #pragma unroll
  for (int q = 0; q < 32; ++q) { float4 v = wh4[q]; whh[4*q]=v.x; whh[4*q+1]=v.y; whh[4*q+2]=v.z; whh[4*q+3]=v.w; }
  float bi = bih[j], bh = bhh[j];
  if (j < 128) h[j] = 0.f;
  __syncthreads();
  for (int t = 0; t < T_; ++t) {
    if (j < 64) xt[j] = frames[((size_t)b * T_ + t) * 64 + j];
    __syncthreads();
    float gi = bi, gh = bh;
    #pragma unroll
    for (int k = 0; k < 64; ++k) gi += xt[k] * wih[k];
    #pragma unroll
    for (int k = 0; k < 128; ++k) gh += h[k] * whh[k];
    GI[j] = gi; GH[j] = gh;
    __syncthreads();
    if (j < 128) {
      float r = 1.f / (1.f + __expf(-(GI[j] + GH[j])));
      float z = 1.f / (1.f + __expf(-(GI[128 + j] + GH[128 + j])));
      float n = tanhf(GI[256 + j] + r * GH[256 + j]);
      h[j] = (1.f - z) * n + z * h[j];
    }
    __syncthreads();
  }
  if (j < 64) {
    float a = bc1[j];
    #pragma unroll 4
    for (int k = 0; k < 128; ++k) a += h[k] * Wc1[k * 64 + j];
    hid[j] = fmaxf(a, 0.f);
  }
  __syncthreads();
  if (j < 2) {
    float o = bc2[j];
    #pragma unroll
    for (int k = 0; k < 64; ++k) o += hid[k] * Wc2[k * 2 + j];
    out[b * 2 + j] = o;
  }
}

// ---------- launch ----------
extern "C" void kernel_launch(void* const* d_in, const int* in_sizes, int n_in,
                              void* d_out, int out_size, void* d_ws, size_t ws_size,
                              hipStream_t stream) {
  const float* x   = (const float*)d_in[0];
  const int*   ei  = (const int*)d_in[1];
  const float* ew  = (const float*)d_in[2];
  const int*   nid = (const int*)d_in[3];
  const float* W1  = (const float*)d_in[4];
  const float* b1  = (const float*)d_in[5];
  const float* W2  = (const float*)d_in[6];
  const float* b2  = (const float*)d_in[7];
  const float* g1  = (const float*)d_in[8];
  const float* be1 = (const float*)d_in[9];
  const float* m1  = (const float*)d_in[10];
  const float* v1  = (const float*)d_in[11];
  const float* g2  = (const float*)d_in[12];
  const float* be2 = (const float*)d_in[13];
  const float* m2  = (const float*)d_in[14];
  const float* v2  = (const float*)d_in[15];
  const float* Wih = (const float*)d_in[16];
  const float* Whh = (const float*)d_in[17];
  const float* bih = (const float*)d_in[18];
  const float* bhh = (const float*)d_in[19];
  const float* Wc1 = (const float*)d_in[20];
  const float* bc1 = (const float*)d_in[21];
  const float* Wc2 = (const float*)d_in[22];
  const float* bc2 = (const float*)d_in[23];
  float* out = (float*)d_out;

  // workspace layout (bytes)
  const size_t REC_OFF  = 0;                       // 62,914,560
  const size_t PL_OFF   = 62914560;                // planes u16: 125,829,120
  const size_t SEG_OFF  = 188743680;               // 3,932,160
  const size_t PERM_OFF = 192675840;               // 1,966,080
  const size_t LENO_OFF = 194641920;               // 1,966,080
  const size_t DV_OFF   = 196608000;               // 1,966,080
  const size_t FR_OFF   = 198574080;               // 122,880
  if (ws_size < (size_t)198696960) return;

  u32* rec   = (u32*)((char*)d_ws + REC_OFF);
  u16* h1    = (u16*)((char*)d_ws + PL_OFF);
  u32* segG  = (u32*)((char*)d_ws + SEG_OFF);
  u32* permG = (u32*)((char*)d_ws + PERM_OFF);
  u32* lenoG = (u32*)((char*)d_ws + LENO_OFF);
  u32* dvG   = (u32*)((char*)d_ws + DV_OFF);
  float* frm = (float*)((char*)d_ws + FR_OFF);

  hipFuncSetAttribute((const void*)kPre, hipFuncAttributeMaxDynamicSharedMemorySize, KP_LDS);
  hipFuncSetAttribute((const void*)kL1,  hipFuncAttributeMaxDynamicSharedMemorySize, L1_LDS);
  hipFuncSetAttribute((const void*)kL2,  hipFuncAttributeMaxDynamicSharedMemorySize, L2_LDS);

  kPre<<<NF, 1024, KP_LDS, stream>>>(ei, ew, nid, rec, segG, permG, lenoG, dvG);
  kL1<<<NF, 512, L1_LDS, stream>>>(x, rec, segG, permG, lenoG, dvG,
                                   W1, b1, g1, be1, m1, v1, h1);
  kL2<<<NF, 512, L2_LDS, stream>>>(rec, segG, lenoG, dvG, h1);
  kB<<<NF, 512, 0, stream>>>(h1, W2, b2, g2, be2, m2, v2, frm);
  kC<<<B_, 384, 0, stream>>>(frm, Wih, Whh, bih, bhh, Wc1, bc1, Wc2, bc2, out);
}

// Round 4
// 977.176 us; speedup vs baseline: 2.6342x; 1.2010x over previous
//
#include <hip/hip_runtime.h>
#include <hip/hip_fp16.h>
#include <stdint.h>

#define B_   16
#define T_   30
#define NF   480       // frames = B*T
#define NN   2048      // nodes
#define EE   32768     // edges
#define EPS  1e-5f

typedef unsigned int u32;
typedef unsigned short u16;
typedef __attribute__((ext_vector_type(8))) short short8;   // 8 bf16 = 4 VGPR
typedef __attribute__((ext_vector_type(4))) float f32x4;    // MFMA C/D frag

// ---------- helpers ----------
__device__ __forceinline__ u16 f2bf(float f) {           // RNE f32->bf16
  u32 u = __float_as_uint(f);
  u32 r = u + 0x7FFFu + ((u >> 16) & 1u);
  return (u16)(r >> 16);
}
__device__ __forceinline__ u32 pack2bf(float a, float b) {
  return (u32)f2bf(a) | ((u32)f2bf(b) << 16);
}
__device__ __forceinline__ float bflo(u32 w) { return __uint_as_float(w << 16); }
__device__ __forceinline__ float bfhi(u32 w) { return __uint_as_float(w & 0xFFFF0000u); }
__device__ __forceinline__ u16 f2h(float f) { return __half_as_ushort(__float2half(f)); }
__device__ __forceinline__ float h2f(u16 h) { return __half2float(__ushort_as_half(h)); }

// =========================================================================
// kPre: sort node_ids, degree, CSR segments, length-bucket, counting-sort
//       records into LDS, coalesced stream-out.  1024 thr, 144KB LDS.
// =========================================================================
#define KP_KEYS 0          // u32[2048]  (also scan aux u32[1024])
#define KP_SEG  8192       // u32[2049]
#define KP_LENO 16400      // u16[2048]
#define KP_HIST 20496      // u32[64]
#define KP_CUR  20752      // u32[64]
#define KP_DINV 131072     // f32[2048]
#define KP_CNT  139264     // u32[2048]
#define KP_REC  0          // u32[32768] phase 2 (keys/seg/leno/hist dead)
#define KP_LDS  147456

__global__ __launch_bounds__(1024) void kPre(
    const int* __restrict__ ei, const float* __restrict__ ew, const int* __restrict__ nid,
    u32* __restrict__ recG, u32* __restrict__ segG, u32* __restrict__ permG,
    u32* __restrict__ lenoG, u32* __restrict__ dvG)
{
  extern __shared__ unsigned char smem[];
  const int g = blockIdx.x, t = threadIdx.x;
  const int*   eig  = ei  + (size_t)g * 2 * EE;
  const float* ewg  = ew  + (size_t)g * EE;
  const int*   nidg = nid + (size_t)g * NN;

  u32*  keys = (u32*)(smem + KP_KEYS);
  u32*  seg  = (u32*)(smem + KP_SEG);
  u16*  leno = (u16*)(smem + KP_LENO);
  u32*  hist = (u32*)(smem + KP_HIST);
  u32*  cur  = (u32*)(smem + KP_CUR);
  float* dinv = (float*)(smem + KP_DINV);
  u32*  cnt  = (u32*)(smem + KP_CNT);
  u32*  rec  = (u32*)(smem + KP_REC);

  // load keys (stable sort: key = nid<<11 | idx), init dinv/cnt
  keys[t]        = ((u32)nidg[t] << 11) | (u32)t;
  keys[t + 1024] = ((u32)nidg[t + 1024] << 11) | (u32)(t + 1024);
  dinv[t] = 1.0f; dinv[t + 1024] = 1.0f;
  cnt[t] = 0u; cnt[t + 1024] = 0u;
  __syncthreads();

  // bitonic sort, 1 pair/thread/pass
  for (int k = 2; k <= NN; k <<= 1) {
    for (int j = k >> 1; j > 0; j >>= 1) {
      int i = ((t & ~(j - 1)) << 1) | (t & (j - 1));
      int l = i | j;
      u32 x = keys[i], y = keys[l];
      bool up = ((i & k) == 0);
      if ((x > y) == up) { keys[i] = y; keys[l] = x; }
      __syncthreads();
    }
  }

  // export perm (u16 pairs packed in u32)
  permG[(size_t)g * 1024 + t] = (keys[2*t] & 2047u) | ((keys[2*t+1] & 2047u) << 16);

  // degree + per-dst histogram
  for (int e = t; e < EE; e += 1024) {
    int d = eig[EE + e];
    atomicAdd(&dinv[d], ewg[e]);
    atomicAdd(&cnt[d], 1u);
  }
  __syncthreads();   // also fences perm-export reads of keys before aux reuse

  float r0 = rsqrtf(dinv[2*t]), r1 = rsqrtf(dinv[2*t+1]);
  dinv[2*t] = r0; dinv[2*t+1] = r1;
  dvG[(size_t)g * 1024 + t] = (u32)f2h(r0 * r0) | ((u32)f2h(r1 * r1) << 16);

  // exclusive scan cnt -> seg
  u32 c0 = cnt[2*t], c1 = cnt[2*t+1];
  u32* aux = keys;                    // keys dead
  aux[t] = c0 + c1;
  __syncthreads();
  for (int off = 1; off < 1024; off <<= 1) {
    u32 v = (t >= off) ? aux[t - off] : 0u;
    __syncthreads();
    aux[t] += v;
    __syncthreads();
  }
  u32 base = (t == 0) ? 0u : aux[t - 1];
  seg[2*t] = base; seg[2*t+1] = base + c0;
  if (t == 0) seg[NN] = aux[1023];
  __syncthreads();

  // export packed segments (start | len<<16)
  {
    u32 s0 = seg[2*t],   l0 = seg[2*t+1] - s0;
    u32 s1_ = seg[2*t+1], l1 = seg[2*t+2] - s1_;
    segG[(size_t)g * 2048 + 2*t]     = (s0  & 0xFFFFu) | (l0 << 16);
    segG[(size_t)g * 2048 + 2*t + 1] = (s1_ & 0xFFFFu) | (l1 << 16);
  }

  // length-bucket slot order (O(N) histogram)
  if (t < 64) hist[t] = 0u;
  __syncthreads();
  for (int i = t; i < NN; i += 1024) {
    u32 len = seg[i+1] - seg[i];
    atomicAdd(&hist[len < 63u ? len : 63u], 1u);
  }
  __syncthreads();
  if (t < 64) {
    u32 v = hist[t], p = v;
    #pragma unroll
    for (int off = 1; off < 64; off <<= 1) {
      u32 o = __shfl_up(p, off, 64);
      if (t >= off) p += o;
    }
    cur[t] = p - v;
  }
  __syncthreads();
  for (int i = t; i < NN; i += 1024) {
    u32 len = seg[i+1] - seg[i];
    u32 slot = atomicAdd(&cur[len < 63u ? len : 63u], 1u);
    leno[slot] = (u16)i;
  }
  __syncthreads();
  lenoG[(size_t)g * 1024 + t] = (u32)leno[2*t] | ((u32)leno[2*t+1] << 16);

  // cursor for counting sort
  cnt[2*t] = seg[2*t]; cnt[2*t+1] = seg[2*t+1];
  __syncthreads();     // after this, keys/seg/leno/hist are dead -> rec overlays

  // counting-sort edges -> rec LDS (src<<16 | f16(norm))
  for (int e = t; e < EE; e += 1024) {
    int s = eig[e], d = eig[EE + e];
    float nrm = dinv[s] * ewg[e] * dinv[d];
    u32 pos = atomicAdd(&cnt[d], 1u);
    rec[pos] = ((u32)s << 16) | (u32)f2h(nrm);
  }
  __syncthreads();

  // coalesced stream-out
  uint4* rg = (uint4*)(recG + (size_t)g * EE);
  const uint4* rl = (const uint4*)rec;
  for (int i = t; i < EE / 4; i += 1024) rg[i] = rl[i];
}

// =========================================================================
// kL1: layer-1.  Aggregate x (8-dim) per dst via record walk (xs in LDS),
//      z[64] = acc @ W1, BN+ReLU, write h1 row-major (128B bf16 node rows).
// =========================================================================
#define L1_XS  0        // f32[2048][8] = 65536 (32B rows, b128-aligned)
#define L1_W1  65536    // f32[512]
#define L1_S1  67584    // f32[64]
#define L1_T1  67840    // f32[64]
#define L1_LDS 68096

__global__ __launch_bounds__(512, 2) void kL1(
    const float* __restrict__ x, const u32* __restrict__ recG, const u32* __restrict__ segG,
    const u32* __restrict__ permG, const u32* __restrict__ lenoG, const u32* __restrict__ dvG,
    const float* __restrict__ W1, const float* __restrict__ b1,
    const float* __restrict__ g1, const float* __restrict__ be1,
    const float* __restrict__ m1, const float* __restrict__ v1,
    u16* __restrict__ h1G)
{
  extern __shared__ unsigned char smem[];
  const int g = blockIdx.x, t = threadIdx.x;
  const u32* recf = recG + (size_t)g * EE;
  float* W1s = (float*)(smem + L1_W1);
  float* s1  = (float*)(smem + L1_S1);
  float* t1  = (float*)(smem + L1_T1);

  // stage permuted x rows
  const u16* pG = (const u16*)(permG + (size_t)g * 1024);
  for (int i = t; i < NN; i += 512) {
    int p = pG[i];
    const float4* xr = (const float4*)(x + ((size_t)g * NN + p) * 8);
    float4 a = xr[0], b = xr[1];
    float4* o = (float4*)(smem + (size_t)i * 32);
    o[0] = a; o[1] = b;
  }
  if (t < 512) W1s[t] = W1[t];
  if (t < 64) {
    float sc = g1[t] * rsqrtf(v1[t] + EPS);
    s1[t] = sc;
    t1[t] = (b1[t] - m1[t]) * sc + be1[t];
  }

  // slot meta (zigzag slot assignment balances walk sums per thread)
  const u16* lG = (const u16*)(lenoG + (size_t)g * 1024);
  const u16* dG = (const u16*)(dvG + (size_t)g * 1024);
  int dA[4], slotA[4]; u32 sA[4], eA[4]; float dvA[4];
  #pragma unroll
  for (int it = 0; it < 4; ++it) {
    int slot = it * 512 + ((it & 1) ? (511 - t) : t);
    int d = lG[slot];
    u32 sp = segG[(size_t)g * 2048 + d];
    slotA[it] = slot; dA[it] = d;
    sA[it] = sp & 0xFFFFu; eA[it] = (sp & 0xFFFFu) + (sp >> 16);
    dvA[it] = h2f(dG[d]);                // = dinv[d]^2
  }
  __syncthreads();

#define P1(RC) { u32 rc_ = (RC); int s_ = (int)(rc_ >> 16); \
    float nm_ = h2f((u16)(rc_ & 0xFFFFu)); \
    const float4* xp_ = (const float4*)(smem + (size_t)s_ * 32); \
    float4 a_ = xp_[0], b_ = xp_[1]; \
    ac0 += nm_*a_.x; ac1 += nm_*a_.y; ac2 += nm_*a_.z; ac3 += nm_*a_.w; \
    ac4 += nm_*b_.x; ac5 += nm_*b_.y; ac6 += nm_*b_.z; ac7 += nm_*b_.w; }

  for (int it = 0; it < 4; ++it) {
    float ac0=0,ac1=0,ac2=0,ac3=0,ac4=0,ac5=0,ac6=0,ac7=0;
    u32 r = sA[it], e = eA[it];
    for (; r + 4 <= e; r += 4) {
      u32 q0 = recf[r], q1 = recf[r+1], q2 = recf[r+2], q3 = recf[r+3];
      P1(q0) P1(q1) P1(q2) P1(q3)
    }
    for (; r < e; ++r) { P1(recf[r]) }
    {  // self-loop (dvA = dinv^2)
      const float4* xd = (const float4*)(smem + (size_t)dA[it] * 32);
      float4 a = xd[0], b = xd[1];
      float dv = dvA[it];
      ac0 += dv*a.x; ac1 += dv*a.y; ac2 += dv*a.z; ac3 += dv*a.w;
      ac4 += dv*b.x; ac5 += dv*b.y; ac6 += dv*b.z; ac7 += dv*b.w;
    }
    float acc[8] = {ac0,ac1,ac2,ac3,ac4,ac5,ac6,ac7};
    float z[64];
    #pragma unroll
    for (int j = 0; j < 64; ++j) z[j] = 0.f;
    #pragma unroll
    for (int k = 0; k < 8; ++k) {
      float f = acc[k];
      const float4* wr = (const float4*)(W1s + k * 64);
      #pragma unroll
      for (int q = 0; q < 16; ++q) {
        float4 w = wr[q];
        z[4*q]   += f * w.x; z[4*q+1] += f * w.y;
        z[4*q+2] += f * w.z; z[4*q+3] += f * w.w;
      }
    }
    // BN + ReLU + bf16 pack, write full 128B node row (row-major)
    int slot = slotA[it];
    uint4* op = (uint4*)h1G + ((size_t)g * NN + slot) * 8;
    #pragma unroll
    for (int p = 0; p < 4; ++p) {
      u32 pk[8];
      #pragma unroll
      for (int j = 0; j < 8; ++j) {
        int f0 = p * 16 + 2 * j;
        float h0 = fmaxf(z[f0]   * s1[f0]   + t1[f0],   0.f);
        float h1v = fmaxf(z[f0+1] * s1[f0+1] + t1[f0+1], 0.f);
        pk[j] = pack2bf(h0, h1v);
      }
      op[p*2]   = make_uint4(pk[0], pk[1], pk[2], pk[3]);
      op[p*2+1] = make_uint4(pk[4], pk[5], pk[6], pk[7]);
    }
  }
#undef P1
}

// =========================================================================
// kL2: layer-2 aggregation, 4 passes of 16 features; h1 16-feat column
//      staged in LDS (node-indexed, 32B rows), agg overwrites h1 in place.
// =========================================================================
#define L2_ST   0        // bf16[2048][16] = 65536
#define L2_LENO 65536    // u16[2048]
#define L2_LDS  69632

__global__ __launch_bounds__(512, 2) void kL2(
    const u32* __restrict__ recG, const u32* __restrict__ segG,
    const u32* __restrict__ lenoG, const u32* __restrict__ dvG,
    u16* __restrict__ h1G)
{
  extern __shared__ unsigned char smem[];
  const int g = blockIdx.x, t = threadIdx.x;
  const u32* recf = recG + (size_t)g * EE;
  u16* lenoL = (u16*)(smem + L2_LENO);

  // stage leno (4KB)
  if (t < 256) ((uint4*)lenoL)[t] = ((const uint4*)(lenoG + (size_t)g * 1024))[t];
  __syncthreads();

  const u16* dG = (const u16*)(dvG + (size_t)g * 1024);
  int dA[4], slotA[4]; u32 sA[4], eA[4]; float dvA[4];
  #pragma unroll
  for (int it = 0; it < 4; ++it) {
    int slot = it * 512 + ((it & 1) ? (511 - t) : t);
    int d = lenoL[slot];
    u32 sp = segG[(size_t)g * 2048 + d];
    slotA[it] = slot; dA[it] = d;
    sA[it] = sp & 0xFFFFu; eA[it] = (sp & 0xFFFFu) + (sp >> 16);
    dvA[it] = h2f(dG[d]);
  }

#define P2(RC) { u32 rc_ = (RC); int s_ = (int)(rc_ >> 16); \
    float nm_ = h2f((u16)(rc_ & 0xFFFFu)); \
    const uint4* rp_ = (const uint4*)(smem + (size_t)s_ * 32); \
    uint4 lo_ = rp_[0], hi_ = rp_[1]; \
    acc[0]+=nm_*bflo(lo_.x);  acc[1]+=nm_*bfhi(lo_.x);  acc[2]+=nm_*bflo(lo_.y);  acc[3]+=nm_*bfhi(lo_.y); \
    acc[4]+=nm_*bflo(lo_.z);  acc[5]+=nm_*bfhi(lo_.z);  acc[6]+=nm_*bflo(lo_.w);  acc[7]+=nm_*bfhi(lo_.w); \
    acc[8]+=nm_*bflo(hi_.x);  acc[9]+=nm_*bfhi(hi_.x);  acc[10]+=nm_*bflo(hi_.y); acc[11]+=nm_*bfhi(hi_.y); \
    acc[12]+=nm_*bflo(hi_.z); acc[13]+=nm_*bfhi(hi_.z); acc[14]+=nm_*bflo(hi_.w); acc[15]+=nm_*bfhi(hi_.w); }

  for (int p = 0; p < 4; ++p) {
    __syncthreads();
    // stage 16-feat column p of all rows, scattered to node rows via leno
    const uint4* plane = (const uint4*)h1G + (size_t)g * NN * 8;
    for (int i = t; i < NN * 2; i += 512) {
      int sl = i >> 1, hf = i & 1;
      uint4 v = plane[(size_t)sl * 8 + p * 2 + hf];
      int d2 = lenoL[sl];
      *(uint4*)(smem + (size_t)d2 * 32 + hf * 16) = v;
    }
    __syncthreads();

    for (int it = 0; it < 4; ++it) {
      float acc[16];
      #pragma unroll
      for (int k = 0; k < 16; ++k) acc[k] = 0.f;
      u32 r = sA[it], e = eA[it];
      for (; r + 4 <= e; r += 4) {
        u32 q0 = recf[r], q1 = recf[r+1], q2 = recf[r+2], q3 = recf[r+3];
        P2(q0) P2(q1) P2(q2) P2(q3)
      }
      for (; r < e; ++r) { P2(recf[r]) }
      {  // self-loop
        const uint4* rd = (const uint4*)(smem + (size_t)dA[it] * 32);
        uint4 lo = rd[0], hi = rd[1];
        float dv = dvA[it];
        acc[0]+=dv*bflo(lo.x);  acc[1]+=dv*bfhi(lo.x);  acc[2]+=dv*bflo(lo.y);  acc[3]+=dv*bfhi(lo.y);
        acc[4]+=dv*bflo(lo.z);  acc[5]+=dv*bfhi(lo.z);  acc[6]+=dv*bflo(lo.w);  acc[7]+=dv*bfhi(lo.w);
        acc[8]+=dv*bflo(hi.x);  acc[9]+=dv*bfhi(hi.x);  acc[10]+=dv*bflo(hi.y); acc[11]+=dv*bfhi(hi.y);
        acc[12]+=dv*bflo(hi.z); acc[13]+=dv*bfhi(hi.z); acc[14]+=dv*bflo(hi.w); acc[15]+=dv*bfhi(hi.w);
      }
      u32 pk[8];
      #pragma unroll
      for (int j = 0; j < 8; ++j) pk[j] = pack2bf(acc[2*j], acc[2*j+1]);
      uint4* op = (uint4*)h1G + ((size_t)g * NN + slotA[it]) * 8 + p * 2;
      op[0] = make_uint4(pk[0], pk[1], pk[2], pk[3]);
      op[1] = make_uint4(pk[4], pk[5], pk[6], pk[7]);
    }
  }
#undef P2
}

// =========================================================================
// kW2p: one-shot prep — W2 (f32 [k][f]) -> bf16 W2bT [f][k]; BN2 fold.
// =========================================================================
__global__ void kW2p(const float* __restrict__ W2, const float* __restrict__ b2,
                     const float* __restrict__ g2, const float* __restrict__ be2,
                     const float* __restrict__ m2, const float* __restrict__ v2,
                     u16* __restrict__ W2bT, float* __restrict__ scG, float* __restrict__ tcG)
{
  const int t = threadIdx.x;    // 256
  for (int i = t; i < 4096; i += 256) {
    int f = i >> 6, k = i & 63;
    W2bT[i] = f2bf(W2[k * 64 + f]);
  }
  if (t < 64) {
    float sc = g2[t] * rsqrtf(v2[t] + EPS);
    scG[t] = sc;
    tcG[t] = (b2[t] - m2[t]) * sc + be2[t];
  }
}

// =========================================================================
// kB: MFMA GEMM  C = agg[2048x64](bf16) @ W2(bf16), fused BN+ReLU+mean.
//     8 waves; wave w owns row-tiles w*16..w*16+15; 4 col-tiles; K=64.
//     A/B frags use the SAME k-slot bijection -> correct for any HW k-map.
// =========================================================================
__global__ __launch_bounds__(512) void kB(
    const u16* __restrict__ agg, const u16* __restrict__ W2bT,
    const float* __restrict__ scG, const float* __restrict__ tcG,
    float* __restrict__ frames)
{
  __shared__ u16 W2s[4096];          // bf16 [f=64][k=64]
  __shared__ float part[8][64];
  const int g = blockIdx.x, tid = threadIdx.x;
  const int l = tid & 63, w = tid >> 6;
  const int lc = l & 15, lg = l >> 4;          // frag col / k-group

  ((uint4*)W2s)[tid] = ((const uint4*)W2bT)[tid];   // 512*16B = 8KB
  __syncthreads();

  // B frags (W2bT rows are f-major: [f][k]) + BN constants, hoisted
  short8 bfr[4][2];
  float scv[4], tcv[4];
  #pragma unroll
  for (int ct = 0; ct < 4; ++ct) {
    #pragma unroll
    for (int kt = 0; kt < 2; ++kt)
      bfr[ct][kt] = *(const short8*)(W2s + (ct * 16 + lc) * 64 + kt * 32 + lg * 8);
    scv[ct] = scG[ct * 16 + lc];
    tcv[ct] = tcG[ct * 16 + lc];
  }

  const u16* ag = agg + (size_t)g * NN * 64;
  float fs0 = 0.f, fs1 = 0.f, fs2 = 0.f, fs3 = 0.f;

  for (int rti = 0; rti < 16; ++rti) {
    int arow = (w * 16 + rti) * 16 + lc;
    const u16* ap = ag + (size_t)arow * 64 + lg * 8;
    short8 a0 = *(const short8*)(ap);
    short8 a1 = *(const short8*)(ap + 32);
#define CTILE(CT, FS) { \
    f32x4 acc = {0.f, 0.f, 0.f, 0.f}; \
    acc = __builtin_amdgcn_mfma_f32_16x16x32_bf16(a0, bfr[CT][0], acc, 0, 0, 0); \
    acc = __builtin_amdgcn_mfma_f32_16x16x32_bf16(a1, bfr[CT][1], acc, 0, 0, 0); \
    float s_ = fmaxf(acc[0] * scv[CT] + tcv[CT], 0.f) \
             + fmaxf(acc[1] * scv[CT] + tcv[CT], 0.f) \
             + fmaxf(acc[2] * scv[CT] + tcv[CT], 0.f) \
             + fmaxf(acc[3] * scv[CT] + tcv[CT], 0.f); \
    s_ += __shfl_xor(s_, 16); \
    s_ += __shfl_xor(s_, 32); \
    FS += s_; }
    CTILE(0, fs0) CTILE(1, fs1) CTILE(2, fs2) CTILE(3, fs3)
#undef CTILE
  }
  if (l < 16) {
    part[w][ 0 + l] = fs0;
    part[w][16 + l] = fs1;
    part[w][32 + l] = fs2;
    part[w][48 + l] = fs3;
  }
  __syncthreads();
  if (tid < 64) {
    float s = 0.f;
    #pragma unroll
    for (int q = 0; q < 8; ++q) s += part[q][tid];
    frames[g * 64 + tid] = s * (1.0f / 2048.0f);
  }
}

// =========================================================================
// kC: GRU over T=30 + classifier; one block per batch element
// =========================================================================
__global__ __launch_bounds__(384, 2) void kC(
    const float* __restrict__ frames,
    const float* __restrict__ Wih, const float* __restrict__ Whh,
    const float* __restrict__ bih, const float* __restrict__ bhh,
    const float* __restrict__ Wc1, const float* __restrict__ bc1,
    const float* __restrict__ Wc2, const float* __restrict__ bc2,
    float* __restrict__ out)
{
  const int b = blockIdx.x;
  const int j = threadIdx.x;     // 384 = 3*TEMP gate rows
  __shared__ float xt[64], h[128], GI[384], GH[384], hid[64];
  float wih[64], whh[128];
  const float4* wi4 = (const float4*)(Wih + (size_t)j * 64);
  #pragma unroll
  for (int q = 0; q < 16; ++q) { float4 v = wi4[q]; wih[4*q]=v.x; wih[4*q+1]=v.y; wih[4*q+2]=v.z; wih[4*q+3]=v.w; }
  const float4* wh4 = (const float4*)(Whh + (size_t)j * 128);
  #pragma unroll
  for (int q = 0; q < 32; ++q) { float4 v = wh4[q]; whh[4*q]=v.x; whh[4*q+1]=v.y; whh[4*q+2]=v.z; whh[4*q+3]=v.w; }
  float bi = bih[j], bh = bhh[j];
  if (j < 128) h[j] = 0.f;
  __syncthreads();
  for (int t = 0; t < T_; ++t) {
    if (j < 64) xt[j] = frames[((size_t)b * T_ + t) * 64 + j];
    __syncthreads();
    float gi = bi, gh = bh;
    #pragma unroll
    for (int k = 0; k < 64; ++k) gi += xt[k] * wih[k];
    #pragma unroll
    for (int k = 0; k < 128; ++k) gh += h[k] * whh[k];
    GI[j] = gi; GH[j] = gh;
    __syncthreads();
    if (j < 128) {
      float r = 1.f / (1.f + __expf(-(GI[j] + GH[j])));
      float z = 1.f / (1.f + __expf(-(GI[128 + j] + GH[128 + j])));
      float n = tanhf(GI[256 + j] + r * GH[256 + j]);
      h[j] = (1.f - z) * n + z * h[j];
    }
    __syncthreads();
  }
  if (j < 64) {
    float a = bc1[j];
    #pragma unroll 4
    for (int k = 0; k < 128; ++k) a += h[k] * Wc1[k * 64 + j];
    hid[j] = fmaxf(a, 0.f);
  }
  __syncthreads();
  if (j < 2) {
    float o = bc2[j];
    #pragma unroll
    for (int k = 0; k < 64; ++k) o += hid[k] * Wc2[k * 2 + j];
    out[b * 2 + j] = o;
  }
}

// ---------- launch ----------
extern "C" void kernel_launch(void* const* d_in, const int* in_sizes, int n_in,
                              void* d_out, int out_size, void* d_ws, size_t ws_size,
                              hipStream_t stream) {
  const float* x   = (const float*)d_in[0];
  const int*   ei  = (const int*)d_in[1];
  const float* ew  = (const float*)d_in[2];
  const int*   nid = (const int*)d_in[3];
  const float* W1  = (const float*)d_in[4];
  const float* b1  = (const float*)d_in[5];
  const float* W2  = (const float*)d_in[6];
  const float* b2  = (const float*)d_in[7];
  const float* g1  = (const float*)d_in[8];
  const float* be1 = (const float*)d_in[9];
  const float* m1  = (const float*)d_in[10];
  const float* v1  = (const float*)d_in[11];
  const float* g2  = (const float*)d_in[12];
  const float* be2 = (const float*)d_in[13];
  const float* m2  = (const float*)d_in[14];
  const float* v2  = (const float*)d_in[15];
  const float* Wih = (const float*)d_in[16];
  const float* Whh = (const float*)d_in[17];
  const float* bih = (const float*)d_in[18];
  const float* bhh = (const float*)d_in[19];
  const float* Wc1 = (const float*)d_in[20];
  const float* bc1 = (const float*)d_in[21];
  const float* Wc2 = (const float*)d_in[22];
  const float* bc2 = (const float*)d_in[23];
  float* out = (float*)d_out;

  // workspace layout (bytes)
  const size_t REC_OFF  = 0;                       // 62,914,560
  const size_t PL_OFF   = 62914560;                // planes u16: 125,829,120
  const size_t SEG_OFF  = 188743680;               // 3,932,160
  const size_t PERM_OFF = 192675840;               // 1,966,080 (dead after kL1 -> reused for W2bT/sc/tc)
  const size_t LENO_OFF = 194641920;               // 1,966,080
  const size_t DV_OFF   = 196608000;               // 1,966,080
  const size_t FR_OFF   = 198574080;               // 122,880
  if (ws_size < (size_t)198696960) return;

  u32* rec   = (u32*)((char*)d_ws + REC_OFF);
  u16* h1    = (u16*)((char*)d_ws + PL_OFF);
  u32* segG  = (u32*)((char*)d_ws + SEG_OFF);
  u32* permG = (u32*)((char*)d_ws + PERM_OFF);
  u32* lenoG = (u32*)((char*)d_ws + LENO_OFF);
  u32* dvG   = (u32*)((char*)d_ws + DV_OFF);
  float* frm = (float*)((char*)d_ws + FR_OFF);
  // W2 prep parked in the perm region (perm is dead after kL1; kW2p runs after kL1)
  u16*   W2bT = (u16*)((char*)d_ws + PERM_OFF);
  float* scG  = (float*)((char*)d_ws + PERM_OFF + 8192);
  float* tcG  = (float*)((char*)d_ws + PERM_OFF + 8448);

  hipFuncSetAttribute((const void*)kPre, hipFuncAttributeMaxDynamicSharedMemorySize, KP_LDS);
  hipFuncSetAttribute((const void*)kL1,  hipFuncAttributeMaxDynamicSharedMemorySize, L1_LDS);
  hipFuncSetAttribute((const void*)kL2,  hipFuncAttributeMaxDynamicSharedMemorySize, L2_LDS);

  kPre<<<NF, 1024, KP_LDS, stream>>>(ei, ew, nid, rec, segG, permG, lenoG, dvG);
  kL1<<<NF, 512, L1_LDS, stream>>>(x, rec, segG, permG, lenoG, dvG,
                                   W1, b1, g1, be1, m1, v1, h1);
  kW2p<<<1, 256, 0, stream>>>(W2, b2, g2, be2, m2, v2, W2bT, scG, tcG);
  kL2<<<NF, 512, L2_LDS, stream>>>(rec, segG, lenoG, dvG, h1);
  kB<<<NF, 512, 0, stream>>>(h1, W2bT, scG, tcG, frm);
  kC<<<B_, 384, 0, stream>>>(frm, Wih, Whh, bih, bhh, Wc1, bc1, Wc2, bc2, out);
}

// Round 5
// 821.038 us; speedup vs baseline: 3.1351x; 1.1902x over previous
//
#include <hip/hip_runtime.h>
#include <hip/hip_fp16.h>
#include <stdint.h>

#define B_   16
#define T_   30
#define NF   480       // frames = B*T
#define NN   2048      // nodes
#define EE   32768     // edges
#define EPS  1e-5f

typedef unsigned int u32;
typedef unsigned short u16;
typedef __attribute__((ext_vector_type(8))) short short8;   // 8 bf16 = 4 VGPR
typedef __attribute__((ext_vector_type(4))) float f32x4;    // MFMA C/D frag

// ---------- helpers ----------
__device__ __forceinline__ u16 f2bf(float f) {           // RNE f32->bf16
  u32 u = __float_as_uint(f);
  u32 r = u + 0x7FFFu + ((u >> 16) & 1u);
  return (u16)(r >> 16);
}
__device__ __forceinline__ u32 pack2bf(float a, float b) {
  return (u32)f2bf(a) | ((u32)f2bf(b) << 16);
}
__device__ __forceinline__ float bflo(u32 w) { return __uint_as_float(w << 16); }
__device__ __forceinline__ float bfhi(u32 w) { return __uint_as_float(w & 0xFFFF0000u); }
__device__ __forceinline__ u16 f2h(float f) { return __half_as_ushort(__float2half(f)); }
__device__ __forceinline__ float h2f(u16 h) { return __half2float(__ushort_as_half(h)); }

// =========================================================================
// kPre: sort node_ids -> perm; degrees; rank dsts by length (desc, exact
//       per-length buckets); JDS offsets; counting-sort edges into JDS
//       layout in LDS (src = ORIG x-row); coalesced stream-out.
// =========================================================================
#define KP_KEYS 0          // u32[2048] (dead before rec overlay)
#define KP_HIST 8192       // u32[256]  (scan scratch; dead before overlay)
#define KP_CUM  9216       // u32[256]
#define KP_CUR  10240      // u32[256]
#define KP_REC  0          // overlay u32[32768] = 131072 B
#define KP_DINV 131072     // f32[2048]
#define KP_CNT  139264     // u32[2048]
#define KP_PERM 147456     // u16[2048]
#define KP_RANK 151552     // u16[2048]
#define KP_OFF  155648     // u32[256]
#define KP_LDS  156672

__global__ __launch_bounds__(1024) void kPre(
    const int* __restrict__ ei, const float* __restrict__ ew, const int* __restrict__ nid,
    u32* __restrict__ recG, u32* __restrict__ metaG, float* __restrict__ dv2G,
    u32* __restrict__ offG)
{
  extern __shared__ unsigned char smem[];
  const int g = blockIdx.x, t = threadIdx.x;
  const int*   eig  = ei  + (size_t)g * 2 * EE;
  const float* ewg  = ew  + (size_t)g * EE;
  const int*   nidg = nid + (size_t)g * NN;

  u32*  keys = (u32*)(smem + KP_KEYS);
  u32*  hist = (u32*)(smem + KP_HIST);
  u32*  cum  = (u32*)(smem + KP_CUM);
  u32*  cur  = (u32*)(smem + KP_CUR);
  u32*  rec  = (u32*)(smem + KP_REC);
  float* dinv = (float*)(smem + KP_DINV);
  u32*  cnt  = (u32*)(smem + KP_CNT);
  u16*  perm = (u16*)(smem + KP_PERM);
  u16*  rank = (u16*)(smem + KP_RANK);
  u32*  off  = (u32*)(smem + KP_OFF);

  // keys (stable sort: key = nid<<11 | idx), init dinv/cnt
  keys[t]        = ((u32)nidg[t] << 11) | (u32)t;
  keys[t + 1024] = ((u32)nidg[t + 1024] << 11) | (u32)(t + 1024);
  dinv[t] = 1.0f; dinv[t + 1024] = 1.0f;
  cnt[t] = 0u; cnt[t + 1024] = 0u;
  __syncthreads();

  // bitonic sort, 1 pair/thread/pass
  for (int k = 2; k <= NN; k <<= 1) {
    for (int j = k >> 1; j > 0; j >>= 1) {
      int i = ((t & ~(j - 1)) << 1) | (t & (j - 1));
      int l = i | j;
      u32 x = keys[i], y = keys[l];
      bool up = ((i & k) == 0);
      if ((x > y) == up) { keys[i] = y; keys[l] = x; }
      __syncthreads();
    }
  }
  perm[2*t]   = (u16)(keys[2*t] & 2047u);
  perm[2*t+1] = (u16)(keys[2*t+1] & 2047u);

  // degree (self-loop weight 1) + per-dst edge count
  for (int e = t; e < EE; e += 1024) {
    int d = eig[EE + e];
    atomicAdd(&dinv[d], ewg[e]);
    atomicAdd(&cnt[d], 1u);
  }
  __syncthreads();
  dinv[2*t]   = rsqrtf(dinv[2*t]);
  dinv[2*t+1] = rsqrtf(dinv[2*t+1]);

  // ---- length histogram (256 buckets, exact for len<255) ----
  if (t < 256) hist[t] = 0u;
  __syncthreads();
  for (int i = t; i < NN; i += 1024) {
    u32 L = cnt[i];
    atomicAdd(&hist[L < 255u ? L : 255u], 1u);
  }
  __syncthreads();
  // inclusive scan hist -> cum
  if (t < 256) cum[t] = hist[t];
  __syncthreads();
  for (int o = 1; o < 256; o <<= 1) {
    u32 v = 0u;
    if (t < 256 && t >= o) v = cum[t - o];
    __syncthreads();
    if (t < 256) cum[t] += v;
    __syncthreads();
  }
  // cntgt[b] = #len > b ; cur = bucket start (descending order)
  if (t < 256) cur[t] = (u32)NN - cum[t];
  __syncthreads();
  // off = exclusive prefix of cntgt (reuse hist as scan buffer)
  if (t < 256) hist[t] = cur[t];
  __syncthreads();
  for (int o = 1; o < 256; o <<= 1) {
    u32 v = 0u;
    if (t < 256 && t >= o) v = hist[t - o];
    __syncthreads();
    if (t < 256) hist[t] += v;
    __syncthreads();
  }
  if (t < 256) {
    u32 ov = hist[t] - cur[t];
    off[t] = ov;
    offG[(size_t)g * 256 + t] = ov;
  }
  __syncthreads();

  // ---- rank assignment (desc length; same-len order arbitrary = valid JDS) ----
  for (int i = t; i < NN; i += 1024) {
    u32 L = cnt[i];
    u32 b = L < 255u ? L : 255u;
    u32 r = atomicAdd(&cur[b], 1u);
    rank[i] = (u16)r;
    metaG[(size_t)g * NN + r] = ((u32)perm[i] << 16) | (L & 0xFFFFu);
    float dv = dinv[i];
    dv2G[(size_t)g * NN + r] = dv * dv;
  }
  __syncthreads();
  // reset cnt as per-dst cursor
  cnt[t] = 0u; cnt[t + 1024] = 0u;
  __syncthreads();   // keys/hist/cum/cur now dead -> rec overlays [0,131072)

  // ---- counting-sort edges into JDS: rec[off[k] + rank[d]] ----
  for (int e = t; e < EE; e += 1024) {
    int s = eig[e], d = eig[EE + e];
    float nrm = dinv[s] * ewg[e] * dinv[d];
    u32 k = atomicAdd(&cnt[d], 1u);
    u32 pos = off[k] + (u32)rank[d];
    rec[pos] = ((u32)perm[s] << 16) | (u32)f2h(nrm);   // src in ORIG x-row space
  }
  __syncthreads();

  // coalesced stream-out
  uint4* rg = (uint4*)(recG + (size_t)g * EE);
  const uint4* rl = (const uint4*)rec;
  for (int i = t; i < EE / 4; i += 1024) rg[i] = rl[i];
}

// =========================================================================
// kL1: JDS walk in 8-dim x space (coalesced rec reads), z = acc@W1,
//      BN+ReLU, h1 -> two 32-feat planes (rank-major rows).
// =========================================================================
#define L1_XS  0        // f32[2048][8] = 65536
#define L1_W1  65536    // f32[512]
#define L1_S1  67584    // f32[64]
#define L1_T1  67840    // f32[64]
#define L1_OFF 68096    // u32[256]
#define L1_LDS 69120

__global__ __launch_bounds__(512, 2) void kL1(
    const float* __restrict__ x, const u32* __restrict__ recG,
    const u32* __restrict__ metaG, const float* __restrict__ dv2G,
    const u32* __restrict__ offG,
    const float* __restrict__ W1, const float* __restrict__ b1,
    const float* __restrict__ g1, const float* __restrict__ be1,
    const float* __restrict__ m1, const float* __restrict__ v1,
    u16* __restrict__ h1G)
{
  extern __shared__ unsigned char smem[];
  const int g = blockIdx.x, t = threadIdx.x;
  const u32* recf = recG + (size_t)g * EE;
  float* W1s = (float*)(smem + L1_W1);
  float* s1  = (float*)(smem + L1_S1);
  float* t1  = (float*)(smem + L1_T1);
  u32*  offL = (u32*)(smem + L1_OFF);

  // stage x DIRECT (orig order, coalesced)
  for (int i = t; i < NN; i += 512) {
    const float4* xr = (const float4*)(x + ((size_t)g * NN + i) * 8);
    float4* o = (float4*)(smem + (size_t)i * 32);
    o[0] = xr[0]; o[1] = xr[1];
  }
  W1s[t] = W1[t];
  if (t < 64) {
    float sc = g1[t] * rsqrtf(v1[t] + EPS);
    s1[t] = sc;
    t1[t] = (b1[t] - m1[t]) * sc + be1[t];
  }
  if (t < 256) offL[t] = offG[(size_t)g * 256 + t];

  // per-slot meta (rank-major, coalesced)
  u32 origA[4], lenA[4]; float dvA[4];
  #pragma unroll
  for (int it = 0; it < 4; ++it) {
    u32 r = it * 512 + t;
    u32 m = metaG[(size_t)g * NN + r];
    origA[it] = m >> 16; lenA[it] = m & 0xFFFFu;
    dvA[it] = dv2G[(size_t)g * NN + r];
  }
  __syncthreads();

#define P1(RC) { u32 rc_ = (RC); u32 s_ = rc_ >> 16; \
    float nm_ = h2f((u16)(rc_ & 0xFFFFu)); \
    const float4* xp_ = (const float4*)(smem + (size_t)s_ * 32); \
    float4 a_ = xp_[0], b_ = xp_[1]; \
    ac0 += nm_*a_.x; ac1 += nm_*a_.y; ac2 += nm_*a_.z; ac3 += nm_*a_.w; \
    ac4 += nm_*b_.x; ac5 += nm_*b_.y; ac6 += nm_*b_.z; ac7 += nm_*b_.w; }

  for (int it = 0; it < 4; ++it) {
    u32 r = (u32)(it * 512 + t);
    float ac0=0,ac1=0,ac2=0,ac3=0,ac4=0,ac5=0,ac6=0,ac7=0;
    int len = (int)lenA[it];
    int j = 0;
    for (; j + 4 <= len; j += 4) {       // JDS: coalesced across lanes
      u32 o0 = offL[j], o1 = offL[j+1], o2 = offL[j+2], o3 = offL[j+3];
      u32 q0 = recf[o0 + r], q1 = recf[o1 + r], q2 = recf[o2 + r], q3 = recf[o3 + r];
      P1(q0) P1(q1) P1(q2) P1(q3)
    }
    for (; j < len; ++j) { P1(recf[offL[j] + r]) }
    {  // self-loop (dv = dinv^2)
      const float4* xd = (const float4*)(smem + (size_t)origA[it] * 32);
      float4 a = xd[0], b = xd[1];
      float dv = dvA[it];
      ac0 += dv*a.x; ac1 += dv*a.y; ac2 += dv*a.z; ac3 += dv*a.w;
      ac4 += dv*b.x; ac5 += dv*b.y; ac6 += dv*b.z; ac7 += dv*b.w;
    }
    float acc[8] = {ac0,ac1,ac2,ac3,ac4,ac5,ac6,ac7};
    float z[64];
    #pragma unroll
    for (int jj = 0; jj < 64; ++jj) z[jj] = 0.f;
    #pragma unroll
    for (int k = 0; k < 8; ++k) {
      float f = acc[k];
      const float4* wr = (const float4*)(W1s + k * 64);
      #pragma unroll
      for (int q = 0; q < 16; ++q) {
        float4 w = wr[q];
        z[4*q]   += f * w.x; z[4*q+1] += f * w.y;
        z[4*q+2] += f * w.z; z[4*q+3] += f * w.w;
      }
    }
    // BN + ReLU + pack; write two 32-feat planes, rank-major (coalesced-ish)
    #pragma unroll
    for (int h = 0; h < 2; ++h) {
      u32 pk[16];
      #pragma unroll
      for (int jj = 0; jj < 16; ++jj) {
        int f0 = h * 32 + 2 * jj;
        float h0 = fmaxf(z[f0]   * s1[f0]   + t1[f0],   0.f);
        float h1v = fmaxf(z[f0+1] * s1[f0+1] + t1[f0+1], 0.f);
        pk[jj] = pack2bf(h0, h1v);
      }
      uint4* op = (uint4*)h1G + ((size_t)(g * 2 + h) * NN + r) * 4;
      op[0] = make_uint4(pk[0], pk[1], pk[2],  pk[3]);
      op[1] = make_uint4(pk[4], pk[5], pk[6],  pk[7]);
      op[2] = make_uint4(pk[8], pk[9], pk[10], pk[11]);
      op[3] = make_uint4(pk[12],pk[13],pk[14], pk[15]);
    }
  }
#undef P1
}

// =========================================================================
// kL2: JDS walk in 64-dim h1 space, 2 passes x 32 feats.  h1 plane staged
//      to LDS by ORIG node row (XOR-swizzled 16B subtiles); agg overwrites
//      h1 planes in place.  1024 thr, 1 blk/CU, 16 waves.
// =========================================================================
#define L2_ST   0        // bf16[2048][32] = 131072 (64B rows, swizzled)
#define L2_META 131072   // u32[2048]
#define L2_OFF  139264   // u32[256]
#define L2_LDS  140288

__global__ __launch_bounds__(1024, 1) void kL2(
    const u32* __restrict__ recG, const u32* __restrict__ metaG,
    const float* __restrict__ dv2G, const u32* __restrict__ offG,
    u16* __restrict__ h1G)
{
  extern __shared__ unsigned char smem[];
  const int g = blockIdx.x, t = threadIdx.x;
  const u32* recf = recG + (size_t)g * EE;
  u32* metaL = (u32*)(smem + L2_META);
  u32* offL  = (u32*)(smem + L2_OFF);

  for (int i = t; i < NN; i += 1024) metaL[i] = metaG[(size_t)g * NN + i];
  if (t < 256) offL[t] = offG[(size_t)g * 256 + t];

  u32 origA[2], lenA[2]; float dvA[2];
  #pragma unroll
  for (int it = 0; it < 2; ++it) {
    u32 r = it * 1024 + t;
    u32 m = metaG[(size_t)g * NN + r];
    origA[it] = m >> 16; lenA[it] = m & 0xFFFFu;
    dvA[it] = dv2G[(size_t)g * NN + r];
  }

#define LD_ROW(S_, W0,W1,W2,W3) { u32 sw_ = (S_) & 3u; \
    const uint4* rp_ = (const uint4*)(smem + (size_t)(S_) * 64); \
    W0 = rp_[0 ^ sw_]; W1 = rp_[1 ^ sw_]; W2 = rp_[2 ^ sw_]; W3 = rp_[3 ^ sw_]; }

#define ACC8(W_, B_) { \
    acc[B_+0]+=nm_*bflo(W_.x); acc[B_+1]+=nm_*bfhi(W_.x); \
    acc[B_+2]+=nm_*bflo(W_.y); acc[B_+3]+=nm_*bfhi(W_.y); \
    acc[B_+4]+=nm_*bflo(W_.z); acc[B_+5]+=nm_*bfhi(W_.z); \
    acc[B_+6]+=nm_*bflo(W_.w); acc[B_+7]+=nm_*bfhi(W_.w); }

#define P2(RC) { u32 rc_ = (RC); u32 s_ = rc_ >> 16; \
    float nm_ = h2f((u16)(rc_ & 0xFFFFu)); \
    uint4 w0_, w1_, w2_, w3_; LD_ROW(s_, w0_, w1_, w2_, w3_) \
    ACC8(w0_, 0) ACC8(w1_, 8) ACC8(w2_, 16) ACC8(w3_, 24) }

  for (int p = 0; p < 2; ++p) {
    __syncthreads();
    // stage plane p: rank-major rows -> LDS row = orig (swizzled subtiles)
    const uint4* plane = (const uint4*)h1G + (size_t)(g * 2 + p) * NN * 4;
    for (int i = t; i < NN * 4; i += 1024) {
      int sl = i >> 2, q = i & 3;
      uint4 v = plane[(size_t)sl * 4 + q];
      u32 orow = metaL[sl] >> 16;
      *(uint4*)(smem + (size_t)orow * 64 + ((u32)q ^ (orow & 3u)) * 16) = v;
    }
    __syncthreads();

    for (int it = 0; it < 2; ++it) {
      u32 r = (u32)(it * 1024 + t);
      float acc[32];
      #pragma unroll
      for (int k = 0; k < 32; ++k) acc[k] = 0.f;
      int len = (int)lenA[it];
      int j = 0;
      for (; j + 2 <= len; j += 2) {
        u32 o0 = offL[j], o1 = offL[j+1];
        u32 q0 = recf[o0 + r], q1 = recf[o1 + r];
        P2(q0) P2(q1)
      }
      if (j < len) { P2(recf[offL[j] + r]) }
      {  // self-loop
        u32 s_ = origA[it];
        float nm_ = dvA[it];
        uint4 w0_, w1_, w2_, w3_; LD_ROW(s_, w0_, w1_, w2_, w3_)
        ACC8(w0_, 0) ACC8(w1_, 8) ACC8(w2_, 16) ACC8(w3_, 24)
      }
      u32 pk[16];
      #pragma unroll
      for (int jj = 0; jj < 16; ++jj) pk[jj] = pack2bf(acc[2*jj], acc[2*jj+1]);
      uint4* op = (uint4*)h1G + ((size_t)(g * 2 + p) * NN + r) * 4;
      op[0] = make_uint4(pk[0], pk[1], pk[2],  pk[3]);
      op[1] = make_uint4(pk[4], pk[5], pk[6],  pk[7]);
      op[2] = make_uint4(pk[8], pk[9], pk[10], pk[11]);
      op[3] = make_uint4(pk[12],pk[13],pk[14], pk[15]);
    }
  }
#undef P2
#undef ACC8
#undef LD_ROW
}

// =========================================================================
// kW2p: one-shot prep — W2 (f32 [k][f]) -> bf16 W2bT [f][k]; BN2 fold.
// =========================================================================
__global__ void kW2p(const float* __restrict__ W2, const float* __restrict__ b2,
                     const float* __restrict__ g2, const float* __restrict__ be2,
                     const float* __restrict__ m2, const float* __restrict__ v2,
                     u16* __restrict__ W2bT, float* __restrict__ scG, float* __restrict__ tcG)
{
  const int t = threadIdx.x;    // 256
  for (int i = t; i < 4096; i += 256) {
    int f = i >> 6, k = i & 63;
    W2bT[i] = f2bf(W2[k * 64 + f]);
  }
  if (t < 64) {
    float sc = g2[t] * rsqrtf(v2[t] + EPS);
    scG[t] = sc;
    tcG[t] = (b2[t] - m2[t]) * sc + be2[t];
  }
}

// =========================================================================
// kB: MFMA GEMM  C = agg[2048x64](bf16, 2 planes) @ W2(bf16), fused
//     BN+ReLU+mean.  A/B frags share one k-slot bijection.
// =========================================================================
__global__ __launch_bounds__(512) void kB(
    const u16* __restrict__ agg, const u16* __restrict__ W2bT,
    const float* __restrict__ scG, const float* __restrict__ tcG,
    float* __restrict__ frames)
{
  __shared__ u16 W2s[4096];          // bf16 [f=64][k=64]
  __shared__ float part[8][64];
  const int g = blockIdx.x, tid = threadIdx.x;
  const int l = tid & 63, w = tid >> 6;
  const int lc = l & 15, lg = l >> 4;          // frag col / k-group

  ((uint4*)W2s)[tid] = ((const uint4*)W2bT)[tid];
  __syncthreads();

  short8 bfr[4][2];
  float scv[4], tcv[4];
  #pragma unroll
  for (int ct = 0; ct < 4; ++ct) {
    #pragma unroll
    for (int kt = 0; kt < 2; ++kt)
      bfr[ct][kt] = *(const short8*)(W2s + (ct * 16 + lc) * 64 + kt * 32 + lg * 8);
    scv[ct] = scG[ct * 16 + lc];
    tcv[ct] = tcG[ct * 16 + lc];
  }

  const u16* p0 = agg + (size_t)(g * 2 + 0) * NN * 32;   // k = 0..31
  const u16* p1 = agg + (size_t)(g * 2 + 1) * NN * 32;   // k = 32..63
  float fs0 = 0.f, fs1 = 0.f, fs2 = 0.f, fs3 = 0.f;

  for (int rti = 0; rti < 16; ++rti) {
    int arow = (w * 16 + rti) * 16 + lc;
    short8 a0 = *(const short8*)(p0 + (size_t)arow * 32 + lg * 8);
    short8 a1 = *(const short8*)(p1 + (size_t)arow * 32 + lg * 8);
#define CTILE(CT, FS) { \
    f32x4 acc = {0.f, 0.f, 0.f, 0.f}; \
    acc = __builtin_amdgcn_mfma_f32_16x16x32_bf16(a0, bfr[CT][0], acc, 0, 0, 0); \
    acc = __builtin_amdgcn_mfma_f32_16x16x32_bf16(a1, bfr[CT][1], acc, 0, 0, 0); \
    float s_ = fmaxf(acc[0] * scv[CT] + tcv[CT], 0.f) \
             + fmaxf(acc[1] * scv[CT] + tcv[CT], 0.f) \
             + fmaxf(acc[2] * scv[CT] + tcv[CT], 0.f) \
             + fmaxf(acc[3] * scv[CT] + tcv[CT], 0.f); \
    s_ += __shfl_xor(s_, 16); \
    s_ += __shfl_xor(s_, 32); \
    FS += s_; }
    CTILE(0, fs0) CTILE(1, fs1) CTILE(2, fs2) CTILE(3, fs3)
#undef CTILE
  }
  if (l < 16) {
    part[w][ 0 + l] = fs0;
    part[w][16 + l] = fs1;
    part[w][32 + l] = fs2;
    part[w][48 + l] = fs3;
  }
  __syncthreads();
  if (tid < 64) {
    float s = 0.f;
    #pragma unroll
    for (int q = 0; q < 8; ++q) s += part[q][tid];
    frames[g * 64 + tid] = s * (1.0f / 2048.0f);
  }
}

// =========================================================================
// kC: GRU over T=30 + classifier; one block per batch element
// =========================================================================
__global__ __launch_bounds__(384, 2) void kC(
    const float* __restrict__ frames,
    const float* __restrict__ Wih, const float* __restrict__ Whh,
    const float* __restrict__ bih, const float* __restrict__ bhh,
    const float* __restrict__ Wc1, const float* __restrict__ bc1,
    const float* __restrict__ Wc2, const float* __restrict__ bc2,
    float* __restrict__ out)
{
  const int b = blockIdx.x;
  const int j = threadIdx.x;     // 384 = 3*TEMP gate rows
  __shared__ float xt[64], h[128], GI[384], GH[384], hid[64];
  float wih[64], whh[128];
  const float4* wi4 = (const float4*)(Wih + (size_t)j * 64);
  #pragma unroll
  for (int q = 0; q < 16; ++q) { float4 v = wi4[q]; wih[4*q]=v.x; wih[4*q+1]=v.y; wih[4*q+2]=v.z; wih[4*q+3]=v.w; }
  const float4* wh4 = (const float4*)(Whh + (size_t)j * 128);
  #pragma unroll
  for (int q = 0; q < 32; ++q) { float4 v = wh4[q]; whh[4*q]=v.x; whh[4*q+1]=v.y; whh[4*q+2]=v.z; whh[4*q+3]=v.w; }
  float bi = bih[j], bh = bhh[j];
  if (j < 128) h[j] = 0.f;
  __syncthreads();
  for (int t = 0; t < T_; ++t) {
    if (j < 64) xt[j] = frames[((size_t)b * T_ + t) * 64 + j];
    __syncthreads();
    float gi = bi, gh = bh;
    #pragma unroll
    for (int k = 0; k < 64; ++k) gi += xt[k] * wih[k];
    #pragma unroll
    for (int k = 0; k < 128; ++k) gh += h[k] * whh[k];
    GI[j] = gi; GH[j] = gh;
    __syncthreads();
    if (j < 128) {
      float r = 1.f / (1.f + __expf(-(GI[j] + GH[j])));
      float z = 1.f / (1.f + __expf(-(GI[128 + j] + GH[128 + j])));
      float n = tanhf(GI[256 + j] + r * GH[256 + j]);
      h[j] = (1.f - z) * n + z * h[j];
    }
    __syncthreads();
  }
  if (j < 64) {
    float a = bc1[j];
    #pragma unroll 4
    for (int k = 0; k < 128; ++k) a += h[k] * Wc1[k * 64 + j];
    hid[j] = fmaxf(a, 0.f);
  }
  __syncthreads();
  if (j < 2) {
    float o = bc2[j];
    #pragma unroll
    for (int k = 0; k < 64; ++k) o += hid[k] * Wc2[k * 2 + j];
    out[b * 2 + j] = o;
  }
}

// ---------- launch ----------
extern "C" void kernel_launch(void* const* d_in, const int* in_sizes, int n_in,
                              void* d_out, int out_size, void* d_ws, size_t ws_size,
                              hipStream_t stream) {
  const float* x   = (const float*)d_in[0];
  const int*   ei  = (const int*)d_in[1];
  const float* ew  = (const float*)d_in[2];
  const int*   nid = (const int*)d_in[3];
  const float* W1  = (const float*)d_in[4];
  const float* b1  = (const float*)d_in[5];
  const float* W2  = (const float*)d_in[6];
  const float* b2  = (const float*)d_in[7];
  const float* g1  = (const float*)d_in[8];
  const float* be1 = (const float*)d_in[9];
  const float* m1  = (const float*)d_in[10];
  const float* v1  = (const float*)d_in[11];
  const float* g2  = (const float*)d_in[12];
  const float* be2 = (const float*)d_in[13];
  const float* m2  = (const float*)d_in[14];
  const float* v2  = (const float*)d_in[15];
  const float* Wih = (const float*)d_in[16];
  const float* Whh = (const float*)d_in[17];
  const float* bih = (const float*)d_in[18];
  const float* bhh = (const float*)d_in[19];
  const float* Wc1 = (const float*)d_in[20];
  const float* bc1 = (const float*)d_in[21];
  const float* Wc2 = (const float*)d_in[22];
  const float* bc2 = (const float*)d_in[23];
  float* out = (float*)d_out;

  // workspace layout (bytes)
  const size_t REC_OFF  = 0;                       // 62,914,560
  const size_t PL_OFF   = 62914560;                // h1/agg planes: 125,829,120
  const size_t META_OFF = 188743680;               // 3,932,160
  const size_t DV2_OFF  = 192675840;               // 3,932,160
  const size_t OFF_OFF  = 196608000;               // 491,520
  const size_t W2_OFF   = 197099520;               // 8192 + 256 + 256
  const size_t FR_OFF   = 197108224;               // 122,880
  if (ws_size < (size_t)197231104) return;

  u32*   rec   = (u32*)((char*)d_ws + REC_OFF);
  u16*   h1    = (u16*)((char*)d_ws + PL_OFF);
  u32*   metaG = (u32*)((char*)d_ws + META_OFF);
  float* dv2G  = (float*)((char*)d_ws + DV2_OFF);
  u32*   offG  = (u32*)((char*)d_ws + OFF_OFF);
  u16*   W2bT  = (u16*)((char*)d_ws + W2_OFF);
  float* scG   = (float*)((char*)d_ws + W2_OFF + 8192);
  float* tcG   = (float*)((char*)d_ws + W2_OFF + 8448);
  float* frm   = (float*)((char*)d_ws + FR_OFF);

  hipFuncSetAttribute((const void*)kPre, hipFuncAttributeMaxDynamicSharedMemorySize, KP_LDS);
  hipFuncSetAttribute((const void*)kL1,  hipFuncAttributeMaxDynamicSharedMemorySize, L1_LDS);
  hipFuncSetAttribute((const void*)kL2,  hipFuncAttributeMaxDynamicSharedMemorySize, L2_LDS);

  kW2p<<<1, 256, 0, stream>>>(W2, b2, g2, be2, m2, v2, W2bT, scG, tcG);
  kPre<<<NF, 1024, KP_LDS, stream>>>(ei, ew, nid, rec, metaG, dv2G, offG);
  kL1<<<NF, 512, L1_LDS, stream>>>(x, rec, metaG, dv2G, offG,
                                   W1, b1, g1, be1, m1, v1, h1);
  kL2<<<NF, 1024, L2_LDS, stream>>>(rec, metaG, dv2G, offG, h1);
  kB<<<NF, 512, 0, stream>>>(h1, W2bT, scG, tcG, frm);
  kC<<<B_, 384, 0, stream>>>(frm, Wih, Whh, bih, bhh, Wc1, bc1, Wc2, bc2, out);
}

// Round 6
// 500.250 us; speedup vs baseline: 5.1455x; 1.6413x over previous
//
#include <hip/hip_runtime.h>
#include <hip/hip_fp16.h>
#include <stdint.h>

#define B_   16
#define T_   30
#define NF   480       // frames = B*T
#define NN   2048      // nodes
#define EE   32768     // edges
#define EPS  1e-5f

typedef unsigned int u32;
typedef unsigned short u16;
typedef __attribute__((ext_vector_type(8))) short short8;   // 8 bf16 = 4 VGPR
typedef __attribute__((ext_vector_type(4))) float f32x4;    // MFMA C/D frag

// ---------- helpers ----------
__device__ __forceinline__ u16 f2bf(float f) {           // RNE f32->bf16
  u32 u = __float_as_uint(f);
  u32 r = u + 0x7FFFu + ((u >> 16) & 1u);
  return (u16)(r >> 16);
}
__device__ __forceinline__ u32 pack2bf(float a, float b) {
  return (u32)f2bf(a) | ((u32)f2bf(b) << 16);
}
__device__ __forceinline__ float bflo(u32 w) { return __uint_as_float(w << 16); }
__device__ __forceinline__ float bfhi(u32 w) { return __uint_as_float(w & 0xFFFF0000u); }
__device__ __forceinline__ u16 f2h(float f) { return __half_as_ushort(__float2half(f)); }
__device__ __forceinline__ float h2f(u16 h) { return __half2float(__ushort_as_half(h)); }

// =========================================================================
// kPre: sort node_ids -> perm; degrees; rank dsts by length (desc, exact
//       per-length buckets); JDS offsets; counting-sort edges into JDS
//       layout in LDS (src = ORIG x-row); coalesced stream-out.
// =========================================================================
#define KP_KEYS 0          // u32[2048] (dead before rec overlay)
#define KP_HIST 8192       // u32[256]  (scan scratch; dead before overlay)
#define KP_CUM  9216       // u32[256]
#define KP_CUR  10240      // u32[256]
#define KP_REC  0          // overlay u32[32768] = 131072 B
#define KP_DINV 131072     // f32[2048]
#define KP_CNT  139264     // u32[2048]
#define KP_PERM 147456     // u16[2048]
#define KP_RANK 151552     // u16[2048]
#define KP_OFF  155648     // u32[256]
#define KP_LDS  156672

__global__ __launch_bounds__(1024) void kPre(
    const int* __restrict__ ei, const float* __restrict__ ew, const int* __restrict__ nid,
    u32* __restrict__ recG, u32* __restrict__ metaG, float* __restrict__ dv2G,
    u32* __restrict__ offG)
{
  extern __shared__ unsigned char smem[];
  const int g = blockIdx.x, t = threadIdx.x;
  const int*   eig  = ei  + (size_t)g * 2 * EE;
  const float* ewg  = ew  + (size_t)g * EE;
  const int*   nidg = nid + (size_t)g * NN;

  u32*  keys = (u32*)(smem + KP_KEYS);
  u32*  hist = (u32*)(smem + KP_HIST);
  u32*  cum  = (u32*)(smem + KP_CUM);
  u32*  cur  = (u32*)(smem + KP_CUR);
  u32*  rec  = (u32*)(smem + KP_REC);
  float* dinv = (float*)(smem + KP_DINV);
  u32*  cnt  = (u32*)(smem + KP_CNT);
  u16*  perm = (u16*)(smem + KP_PERM);
  u16*  rank = (u16*)(smem + KP_RANK);
  u32*  off  = (u32*)(smem + KP_OFF);

  // keys (stable sort: key = nid<<11 | idx), init dinv/cnt
  keys[t]        = ((u32)nidg[t] << 11) | (u32)t;
  keys[t + 1024] = ((u32)nidg[t + 1024] << 11) | (u32)(t + 1024);
  dinv[t] = 1.0f; dinv[t + 1024] = 1.0f;
  cnt[t] = 0u; cnt[t + 1024] = 0u;
  __syncthreads();

  // bitonic sort, 1 pair/thread/pass
  for (int k = 2; k <= NN; k <<= 1) {
    for (int j = k >> 1; j > 0; j >>= 1) {
      int i = ((t & ~(j - 1)) << 1) | (t & (j - 1));
      int l = i | j;
      u32 x = keys[i], y = keys[l];
      bool up = ((i & k) == 0);
      if ((x > y) == up) { keys[i] = y; keys[l] = x; }
      __syncthreads();
    }
  }
  perm[2*t]   = (u16)(keys[2*t] & 2047u);
  perm[2*t+1] = (u16)(keys[2*t+1] & 2047u);

  // degree (self-loop weight 1) + per-dst edge count
  for (int e = t; e < EE; e += 1024) {
    int d = eig[EE + e];
    atomicAdd(&dinv[d], ewg[e]);
    atomicAdd(&cnt[d], 1u);
  }
  __syncthreads();
  dinv[2*t]   = rsqrtf(dinv[2*t]);
  dinv[2*t+1] = rsqrtf(dinv[2*t+1]);

  // ---- length histogram (256 buckets, exact for len<255) ----
  if (t < 256) hist[t] = 0u;
  __syncthreads();
  for (int i = t; i < NN; i += 1024) {
    u32 L = cnt[i];
    atomicAdd(&hist[L < 255u ? L : 255u], 1u);
  }
  __syncthreads();
  // inclusive scan hist -> cum
  if (t < 256) cum[t] = hist[t];
  __syncthreads();
  for (int o = 1; o < 256; o <<= 1) {
    u32 v = 0u;
    if (t < 256 && t >= o) v = cum[t - o];
    __syncthreads();
    if (t < 256) cum[t] += v;
    __syncthreads();
  }
  // cntgt[b] = #len > b ; cur = bucket start (descending order)
  if (t < 256) cur[t] = (u32)NN - cum[t];
  __syncthreads();
  // off = exclusive prefix of cntgt (reuse hist as scan buffer)
  if (t < 256) hist[t] = cur[t];
  __syncthreads();
  for (int o = 1; o < 256; o <<= 1) {
    u32 v = 0u;
    if (t < 256 && t >= o) v = hist[t - o];
    __syncthreads();
    if (t < 256) hist[t] += v;
    __syncthreads();
  }
  if (t < 256) {
    u32 ov = hist[t] - cur[t];
    off[t] = ov;
    offG[(size_t)g * 256 + t] = ov;
  }
  __syncthreads();

  // ---- rank assignment (desc length; same-len order arbitrary = valid JDS) ----
  for (int i = t; i < NN; i += 1024) {
    u32 L = cnt[i];
    u32 b = L < 255u ? L : 255u;
    u32 r = atomicAdd(&cur[b], 1u);
    rank[i] = (u16)r;
    metaG[(size_t)g * NN + r] = ((u32)perm[i] << 16) | (L & 0xFFFFu);
    float dv = dinv[i];
    dv2G[(size_t)g * NN + r] = dv * dv;
  }
  __syncthreads();
  // reset cnt as per-dst cursor
  cnt[t] = 0u; cnt[t + 1024] = 0u;
  __syncthreads();   // keys/hist/cum/cur now dead -> rec overlays [0,131072)

  // ---- counting-sort edges into JDS: rec[off[k] + rank[d]] ----
  for (int e = t; e < EE; e += 1024) {
    int s = eig[e], d = eig[EE + e];
    float nrm = dinv[s] * ewg[e] * dinv[d];
    u32 k = atomicAdd(&cnt[d], 1u);
    u32 pos = off[k] + (u32)rank[d];
    rec[pos] = ((u32)perm[s] << 16) | (u32)f2h(nrm);   // src in ORIG x-row space
  }
  __syncthreads();

  // coalesced stream-out
  uint4* rg = (uint4*)(recG + (size_t)g * EE);
  const uint4* rl = (const uint4*)rec;
  for (int i = t; i < EE / 4; i += 1024) rg[i] = rl[i];
}

// =========================================================================
// kFuse: walk-1 in 8-dim x space (agg8 kept in regs), then 4 passes of
//   16 features: h1-slice = ReLU(BN(agg8@W1half)) computed from regs,
//   scattered bf16 into LDS (orig rows), walk-2 accumulates, writes agg2
//   sub-planes (fully coalesced 16B-row stores).  1024 thr, 69KB LDS,
//   launch_bounds(1024,8) -> VGPR<=64 -> 2 blocks/CU.
// =========================================================================
#define KF_XS   0        // f32[2048][8] = 65536 ; pass-phase: bf16 h1 [2048][16] 32B rows
#define KF_OFF  65536    // u32[256]
#define KF_W1   66560    // f32[512]
#define KF_S1   68608    // f32[64]
#define KF_T1   68864    // f32[64]
#define KF_LDS  69120

__global__ __launch_bounds__(1024, 8) void kFuse(
    const float* __restrict__ x, const u32* __restrict__ recG,
    const u32* __restrict__ metaG, const float* __restrict__ dv2G,
    const u32* __restrict__ offG,
    const float* __restrict__ W1, const float* __restrict__ b1,
    const float* __restrict__ g1, const float* __restrict__ be1,
    const float* __restrict__ m1, const float* __restrict__ v1,
    u16* __restrict__ aggG)
{
  extern __shared__ unsigned char smem[];
  const int g = blockIdx.x, t = threadIdx.x;
  const u32* recf = recG + (size_t)g * EE;
  u32*  offL = (u32*)(smem + KF_OFF);
  float* W1s = (float*)(smem + KF_W1);
  float* s1  = (float*)(smem + KF_S1);
  float* t1  = (float*)(smem + KF_T1);

  // stage x rows (orig order, coalesced)
  for (int i = t; i < NN; i += 1024) {
    const float4* xr = (const float4*)(x + ((size_t)g * NN + i) * 8);
    float4* o = (float4*)(smem + (size_t)i * 32);
    o[0] = xr[0]; o[1] = xr[1];
  }
  if (t < 256) offL[t] = offG[(size_t)g * 256 + t];
  if (t < 512) W1s[t] = W1[t];
  if (t < 64) {
    float sc = g1[t] * rsqrtf(v1[t] + EPS);
    s1[t] = sc;
    t1[t] = (b1[t] - m1[t]) * sc + be1[t];
  }

  u32 origA[2], lenA[2]; float dvA[2];
  #pragma unroll
  for (int it = 0; it < 2; ++it) {
    u32 r = (u32)(it * 1024 + t);
    u32 m = metaG[(size_t)g * NN + r];
    origA[it] = m >> 16; lenA[it] = m & 0xFFFFu;
    dvA[it] = dv2G[(size_t)g * NN + r];
  }
  __syncthreads();

  // ---- walk-1: aggregate x (8-dim), agg stays in registers ----
  float agg[2][8];
#define P1(RC) { u32 rc_ = (RC); u32 s_ = rc_ >> 16; \
    float nm_ = h2f((u16)(rc_ & 0xFFFFu)); \
    const float4* xp_ = (const float4*)(smem + (size_t)s_ * 32); \
    float4 a_ = xp_[0], b_ = xp_[1]; \
    ac0 += nm_*a_.x; ac1 += nm_*a_.y; ac2 += nm_*a_.z; ac3 += nm_*a_.w; \
    ac4 += nm_*b_.x; ac5 += nm_*b_.y; ac6 += nm_*b_.z; ac7 += nm_*b_.w; }
  #pragma unroll
  for (int it = 0; it < 2; ++it) {
    u32 r = (u32)(it * 1024 + t);
    float ac0=0,ac1=0,ac2=0,ac3=0,ac4=0,ac5=0,ac6=0,ac7=0;
    int len = (int)lenA[it];
    int j = 0;
    for (; j + 4 <= len; j += 4) {       // JDS: contiguous across lanes
      u32 o0 = offL[j], o1 = offL[j+1], o2 = offL[j+2], o3 = offL[j+3];
      u32 q0 = recf[o0 + r], q1 = recf[o1 + r], q2 = recf[o2 + r], q3 = recf[o3 + r];
      P1(q0) P1(q1) P1(q2) P1(q3)
    }
    for (; j < len; ++j) { P1(recf[offL[j] + r]) }
    {  // self-loop (dv = dinv^2)
      const float4* xd = (const float4*)(smem + (size_t)origA[it] * 32);
      float4 a = xd[0], b = xd[1];
      float dv = dvA[it];
      ac0 += dv*a.x; ac1 += dv*a.y; ac2 += dv*a.z; ac3 += dv*a.w;
      ac4 += dv*b.x; ac5 += dv*b.y; ac6 += dv*b.z; ac7 += dv*b.w;
    }
    agg[it][0]=ac0; agg[it][1]=ac1; agg[it][2]=ac2; agg[it][3]=ac3;
    agg[it][4]=ac4; agg[it][5]=ac5; agg[it][6]=ac6; agg[it][7]=ac7;
  }
#undef P1

  // ---- 4 passes x 16 features: build h1 slice in LDS, walk-2, store ----
#define ACC8(W_, B_) { \
    acc[B_+0]+=nm_*bflo(W_.x); acc[B_+1]+=nm_*bfhi(W_.x); \
    acc[B_+2]+=nm_*bflo(W_.y); acc[B_+3]+=nm_*bfhi(W_.y); \
    acc[B_+4]+=nm_*bflo(W_.z); acc[B_+5]+=nm_*bfhi(W_.z); \
    acc[B_+6]+=nm_*bflo(W_.w); acc[B_+7]+=nm_*bfhi(W_.w); }
#define P2(RC) { u32 rc_ = (RC); u32 s_ = rc_ >> 16; \
    float nm_ = h2f((u16)(rc_ & 0xFFFFu)); \
    u32 sw_ = s_ & 1u; \
    const uint4* rp_ = (const uint4*)(smem + (size_t)s_ * 32); \
    uint4 w0_ = rp_[sw_], w1_ = rp_[1u ^ sw_]; \
    ACC8(w0_, 0) ACC8(w1_, 8) }

  for (int p = 0; p < 4; ++p) {
    __syncthreads();    // xs readers (p==0) / previous pass h1 readers done
    #pragma unroll
    for (int it = 0; it < 2; ++it) {
      float z[16];
      #pragma unroll
      for (int j = 0; j < 16; ++j) z[j] = 0.f;
      #pragma unroll
      for (int k = 0; k < 8; ++k) {
        float f = agg[it][k];
        #pragma unroll
        for (int j = 0; j < 16; ++j) z[j] += f * W1s[k * 64 + p * 16 + j];
      }
      u32 pk[8];
      #pragma unroll
      for (int j = 0; j < 8; ++j) {
        int f0 = p * 16 + 2 * j;
        float h0 = fmaxf(z[2*j]   * s1[f0]   + t1[f0],   0.f);
        float h1v = fmaxf(z[2*j+1] * s1[f0+1] + t1[f0+1], 0.f);
        pk[j] = pack2bf(h0, h1v);
      }
      u32 orow = origA[it], sw = orow & 1u;
      uint4* lp = (uint4*)(smem + (size_t)orow * 32);
      lp[sw]      = make_uint4(pk[0], pk[1], pk[2], pk[3]);
      lp[1u ^ sw] = make_uint4(pk[4], pk[5], pk[6], pk[7]);
    }
    __syncthreads();
    #pragma unroll
    for (int it = 0; it < 2; ++it) {
      u32 r = (u32)(it * 1024 + t);
      float acc[16];
      #pragma unroll
      for (int k = 0; k < 16; ++k) acc[k] = 0.f;
      int len = (int)lenA[it];
      int j = 0;
      for (; j + 2 <= len; j += 2) {
        u32 o0 = offL[j], o1 = offL[j+1];
        u32 q0 = recf[o0 + r], q1 = recf[o1 + r];
        P2(q0) P2(q1)
      }
      if (j < len) { P2(recf[offL[j] + r]) }
      {  // self-loop
        u32 s_ = origA[it];
        float nm_ = dvA[it];
        u32 sw_ = s_ & 1u;
        const uint4* rp_ = (const uint4*)(smem + (size_t)s_ * 32);
        uint4 w0_ = rp_[sw_], w1_ = rp_[1u ^ sw_];
        ACC8(w0_, 0) ACC8(w1_, 8)
      }
      u32 pk[8];
      #pragma unroll
      for (int jj = 0; jj < 8; ++jj) pk[jj] = pack2bf(acc[2*jj], acc[2*jj+1]);
      // sub-plane f8 = p*2+q, 16B rows -> per-inst lane-contiguous stores
      uint4* op0 = (uint4*)aggG + (size_t)(g * 8 + p * 2    ) * NN + r;
      uint4* op1 = (uint4*)aggG + (size_t)(g * 8 + p * 2 + 1) * NN + r;
      *op0 = make_uint4(pk[0], pk[1], pk[2], pk[3]);
      *op1 = make_uint4(pk[4], pk[5], pk[6], pk[7]);
    }
  }
#undef P2
#undef ACC8
}

// =========================================================================
// kW2p: one-shot prep — W2 (f32 [k][f]) -> bf16 W2bT [f][k]; BN2 fold.
// =========================================================================
__global__ void kW2p(const float* __restrict__ W2, const float* __restrict__ b2,
                     const float* __restrict__ g2, const float* __restrict__ be2,
                     const float* __restrict__ m2, const float* __restrict__ v2,
                     u16* __restrict__ W2bT, float* __restrict__ scG, float* __restrict__ tcG)
{
  const int t = threadIdx.x;    // 256
  for (int i = t; i < 4096; i += 256) {
    int f = i >> 6, k = i & 63;
    W2bT[i] = f2bf(W2[k * 64 + f]);
  }
  if (t < 64) {
    float sc = g2[t] * rsqrtf(v2[t] + EPS);
    scG[t] = sc;
    tcG[t] = (b2[t] - m2[t]) * sc + be2[t];
  }
}

// =========================================================================
// kB: MFMA GEMM  C = agg2[2048x64](bf16, 8 sub-planes) @ W2(bf16), fused
//     BN+ReLU+mean.  A/B frags share one k-slot bijection.
// =========================================================================
__global__ __launch_bounds__(512) void kB(
    const u16* __restrict__ agg, const u16* __restrict__ W2bT,
    const float* __restrict__ scG, const float* __restrict__ tcG,
    float* __restrict__ frames)
{
  __shared__ u16 W2s[4096];          // bf16 [f=64][k=64]
  __shared__ float part[8][64];
  const int g = blockIdx.x, tid = threadIdx.x;
  const int l = tid & 63, w = tid >> 6;
  const int lc = l & 15, lg = l >> 4;          // frag col / k-group

  ((uint4*)W2s)[tid] = ((const uint4*)W2bT)[tid];
  __syncthreads();

  short8 bfr[4][2];
  float scv[4], tcv[4];
  #pragma unroll
  for (int ct = 0; ct < 4; ++ct) {
    #pragma unroll
    for (int kt = 0; kt < 2; ++kt)
      bfr[ct][kt] = *(const short8*)(W2s + (ct * 16 + lc) * 64 + kt * 32 + lg * 8);
    scv[ct] = scG[ct * 16 + lc];
    tcv[ct] = tcG[ct * 16 + lc];
  }

  const u16* base = agg + (size_t)g * (8 * NN * 8);   // 8 sub-planes x NN x 8 u16
  float fs0 = 0.f, fs1 = 0.f, fs2 = 0.f, fs3 = 0.f;

  for (int rti = 0; rti < 16; ++rti) {
    int arow = (w * 16 + rti) * 16 + lc;
    short8 a0 = *(const short8*)(base + ((size_t)(0 * 4 + lg) * NN + arow) * 8);
    short8 a1 = *(const short8*)(base + ((size_t)(1 * 4 + lg) * NN + arow) * 8);
#define CTILE(CT, FS) { \
    f32x4 acc = {0.f, 0.f, 0.f, 0.f}; \
    acc = __builtin_amdgcn_mfma_f32_16x16x32_bf16(a0, bfr[CT][0], acc, 0, 0, 0); \
    acc = __builtin_amdgcn_mfma_f32_16x16x32_bf16(a1, bfr[CT][1], acc, 0, 0, 0); \
    float s_ = fmaxf(acc[0] * scv[CT] + tcv[CT], 0.f) \
             + fmaxf(acc[1] * scv[CT] + tcv[CT], 0.f) \
             + fmaxf(acc[2] * scv[CT] + tcv[CT], 0.f) \
             + fmaxf(acc[3] * scv[CT] + tcv[CT], 0.f); \
    s_ += __shfl_xor(s_, 16); \
    s_ += __shfl_xor(s_, 32); \
    FS += s_; }
    CTILE(0, fs0) CTILE(1, fs1) CTILE(2, fs2) CTILE(3, fs3)
#undef CTILE
  }
  if (l < 16) {
    part[w][ 0 + l] = fs0;
    part[w][16 + l] = fs1;
    part[w][32 + l] = fs2;
    part[w][48 + l] = fs3;
  }
  __syncthreads();
  if (tid < 64) {
    float s = 0.f;
    #pragma unroll
    for (int q = 0; q < 8; ++q) s += part[q][tid];
    frames[g * 64 + tid] = s * (1.0f / 2048.0f);
  }
}

// =========================================================================
// kC: GRU over T=30 + classifier; one block per batch element
// =========================================================================
__global__ __launch_bounds__(384, 2) void kC(
    const float* __restrict__ frames,
    const float* __restrict__ Wih, const float* __restrict__ Whh,
    const float* __restrict__ bih, const float* __restrict__ bhh,
    const float* __restrict__ Wc1, const float* __restrict__ bc1,
    const float* __restrict__ Wc2, const float* __restrict__ bc2,
    float* __restrict__ out)
{
  const int b = blockIdx.x;
  const int j = threadIdx.x;     // 384 = 3*TEMP gate rows
  __shared__ float xt[64], h[128], GI[384], GH[384], hid[64];
  float wih[64], whh[128];
  const float4* wi4 = (const float4*)(Wih + (size_t)j * 64);
  #pragma unroll
  for (int q = 0; q < 16; ++q) { float4 v = wi4[q]; wih[4*q]=v.x; wih[4*q+1]=v.y; wih[4*q+2]=v.z; wih[4*q+3]=v.w; }
  const float4* wh4 = (const float4*)(Whh + (size_t)j * 128);
  #pragma unroll
  for (int q = 0; q < 32; ++q) { float4 v = wh4[q]; whh[4*q]=v.x; whh[4*q+1]=v.y; whh[4*q+2]=v.z; whh[4*q+3]=v.w; }
  float bi = bih[j], bh = bhh[j];
  if (j < 128) h[j] = 0.f;
  __syncthreads();
  for (int t = 0; t < T_; ++t) {
    if (j < 64) xt[j] = frames[((size_t)b * T_ + t) * 64 + j];
    __syncthreads();
    float gi = bi, gh = bh;
    #pragma unroll
    for (int k = 0; k < 64; ++k) gi += xt[k] * wih[k];
    #pragma unroll
    for (int k = 0; k < 128; ++k) gh += h[k] * whh[k];
    GI[j] = gi; GH[j] = gh;
    __syncthreads();
    if (j < 128) {
      float r = 1.f / (1.f + __expf(-(GI[j] + GH[j])));
      float z = 1.f / (1.f + __expf(-(GI[128 + j] + GH[128 + j])));
      float n = tanhf(GI[256 + j] + r * GH[256 + j]);
      h[j] = (1.f - z) * n + z * h[j];
    }
    __syncthreads();
  }
  if (j < 64) {
    float a = bc1[j];
    #pragma unroll 4
    for (int k = 0; k < 128; ++k) a += h[k] * Wc1[k * 64 + j];
    hid[j] = fmaxf(a, 0.f);
  }
  __syncthreads();
  if (j < 2) {
    float o = bc2[j];
    #pragma unroll
    for (int k = 0; k < 64; ++k) o += hid[k] * Wc2[k * 2 + j];
    out[b * 2 + j] = o;
  }
}

// ---------- launch ----------
extern "C" void kernel_launch(void* const* d_in, const int* in_sizes, int n_in,
                              void* d_out, int out_size, void* d_ws, size_t ws_size,
                              hipStream_t stream) {
  const float* x   = (const float*)d_in[0];
  const int*   ei  = (const int*)d_in[1];
  const float* ew  = (const float*)d_in[2];
  const int*   nid = (const int*)d_in[3];
  const float* W1  = (const float*)d_in[4];
  const float* b1  = (const float*)d_in[5];
  const float* W2  = (const float*)d_in[6];
  const float* b2  = (const float*)d_in[7];
  const float* g1  = (const float*)d_in[8];
  const float* be1 = (const float*)d_in[9];
  const float* m1  = (const float*)d_in[10];
  const float* v1  = (const float*)d_in[11];
  const float* g2  = (const float*)d_in[12];
  const float* be2 = (const float*)d_in[13];
  const float* m2  = (const float*)d_in[14];
  const float* v2  = (const float*)d_in[15];
  const float* Wih = (const float*)d_in[16];
  const float* Whh = (const float*)d_in[17];
  const float* bih = (const float*)d_in[18];
  const float* bhh = (const float*)d_in[19];
  const float* Wc1 = (const float*)d_in[20];
  const float* bc1 = (const float*)d_in[21];
  const float* Wc2 = (const float*)d_in[22];
  const float* bc2 = (const float*)d_in[23];
  float* out = (float*)d_out;

  // workspace layout (bytes) — identical footprint to round 4/5 (197.2 MB)
  const size_t REC_OFF  = 0;                       // 62,914,560
  const size_t PL_OFF   = 62914560;                // agg2 8-subplane bf16: 125,829,120
  const size_t META_OFF = 188743680;               // 3,932,160
  const size_t DV2_OFF  = 192675840;               // 3,932,160
  const size_t OFF_OFF  = 196608000;               // 491,520
  const size_t W2_OFF   = 197099520;               // 8192 + 256 + 256
  const size_t FR_OFF   = 197108224;               // 122,880
  if (ws_size < (size_t)197231104) return;

  u32*   rec   = (u32*)((char*)d_ws + REC_OFF);
  u16*   agg2  = (u16*)((char*)d_ws + PL_OFF);
  u32*   metaG = (u32*)((char*)d_ws + META_OFF);
  float* dv2G  = (float*)((char*)d_ws + DV2_OFF);
  u32*   offG  = (u32*)((char*)d_ws + OFF_OFF);
  u16*   W2bT  = (u16*)((char*)d_ws + W2_OFF);
  float* scG   = (float*)((char*)d_ws + W2_OFF + 8192);
  float* tcG   = (float*)((char*)d_ws + W2_OFF + 8448);
  float* frm   = (float*)((char*)d_ws + FR_OFF);

  hipFuncSetAttribute((const void*)kPre,  hipFuncAttributeMaxDynamicSharedMemorySize, KP_LDS);
  hipFuncSetAttribute((const void*)kFuse, hipFuncAttributeMaxDynamicSharedMemorySize, KF_LDS);

  kW2p<<<1, 256, 0, stream>>>(W2, b2, g2, be2, m2, v2, W2bT, scG, tcG);
  kPre<<<NF, 1024, KP_LDS, stream>>>(ei, ew, nid, rec, metaG, dv2G, offG);
  kFuse<<<NF, 1024, KF_LDS, stream>>>(x, rec, metaG, dv2G, offG,
                                      W1, b1, g1, be1, m1, v1, agg2);
  kB<<<NF, 512, 0, stream>>>(agg2, W2bT, scG, tcG, frm);
  kC<<<B_, 384, 0, stream>>>(frm, Wih, Whh, bih, bhh, Wc1, bc1, Wc2, bc2, out);
}